// Round 7
// baseline (200.901 us; speedup 1.0000x reference)
//
#include <hip/hip_runtime.h>

typedef __attribute__((ext_vector_type(8))) short bf16x8;
typedef __attribute__((ext_vector_type(4))) float f32x4;
typedef unsigned short u16;
typedef unsigned int u32;

#define DEV static __device__ __forceinline__

// problem sizes (fixed by the reference)
#define CB 4
#define CN 2048
#define CD 1024
#define CM 8192   // CB*CN

DEV u16 f2bf(float f) {
  u32 u = __float_as_uint(f);
  u = (u + 0x7FFFu + ((u >> 16) & 1u)) >> 16;
  return (u16)u;
}
DEV float bf2f(u16 h) { return __uint_as_float(((u32)h) << 16); }

#define GLD16(gsrc, ldst)                                                        \
  __builtin_amdgcn_global_load_lds(                                              \
      (const __attribute__((address_space(1))) void*)(gsrc),                     \
      (__attribute__((address_space(3))) void*)(ldst), 16, 0, 0)

#define SBAR()  asm volatile("s_barrier" ::: "memory")
#define WAITL() asm volatile("s_waitcnt lgkmcnt(0)" ::: "memory")
#define WAITV4() asm volatile("s_waitcnt vmcnt(4)" ::: "memory")
#define WAITV3() asm volatile("s_waitcnt vmcnt(3)" ::: "memory")
#define WAITV0() asm volatile("s_waitcnt vmcnt(0)" ::: "memory")

// ---------------------------------------------------------------------------
// BK=32 LDS tiles: [rows][32 k] bf16, 64B per row (4 x 16B slots).
// Swizzle: slot ^= (row&3) ^ ((row>>2)&3)  (bijective per row, involution).
// Uniformity over 16B slots -> conflict-free wave64 ds_read_b128 (same
// argument as the verified 128B-row layout: 8 lanes per 4-bank group).
// ---------------------------------------------------------------------------
DEV bf16x8 lds_read8(const short* region, int row, int kelem) {
  int b = row * 64 + kelem * 2;
  b ^= (((row & 3) ^ ((row >> 2) & 3)) << 4);
  return *(const bf16x8*)((const char*)region + b);
}

// stage 256 rows x 32 k (16KB, 1024 chunks, 2 per thread), pre-swizzled src
DEV void stage256(const u16* __restrict__ g, int ld, int row0, int kb,
                  short* dst, int tid) {
#pragma unroll
  for (int s = 0; s < 2; ++s) {
    const int c = tid + s * 512;
    const int row = c >> 2, sl = c & 3;
    const int lo = sl ^ (row & 3) ^ ((row >> 2) & 3);
    GLD16(g + (size_t)(row0 + row) * ld + kb + lo * 8, (char*)dst + c * 16);
  }
}

// stage 128 rows x 32 k (8KB, 512 chunks, 1 per thread)
DEV void stage128(const u16* __restrict__ g, int ld, int row0, int kb,
                  short* dst, int tid) {
  const int c = tid;
  const int row = c >> 2, sl = c & 3;
  const int lo = sl ^ (row & 3) ^ ((row >> 2) & 3);
  GLD16(g + (size_t)(row0 + row) * ld + kb + lo * 8, (char*)dst + c * 16);
}

// ---------------------------------------------------------------------------
// 256x256 triple-buffer core. 8 waves (2x4), wave tile 128x64, acc[8][4].
// LDS 96KB = 3 buffers x (A 256x32 @0 + B 256x32 @8192 shorts).
// Per tile t: issue stage(t+2) -> buf[(t+2)%3]; ds_read 12 frags; 32-MFMA
// cluster; vmcnt(4) [drains t+1's loads - full tile of cover - keeps t+2's
// 4 in flight across the barrier]; s_barrier.  Tails: vmcnt(0).
// Race ledger: buf[(t+2)%3] is unread during tiles t,t+1 (last read t-1,
// separated by barriers); t+1's buffer fully landed before its first read.
// ---------------------------------------------------------------------------
DEV void gemm_core8(const u16* __restrict__ A, int lda,
                    const u16* __restrict__ Bt, int ldb,
                    int m0, int n0, int K, short* lds, f32x4 (&acc)[8][4])
{
  const int tid = threadIdx.x;
  const int lane = tid & 63;
  const int wid = tid >> 6;
  const int wr = wid >> 2, wc = wid & 3;
  const int lr = lane & 15, kg = lane >> 4;
  const int nt = K >> 5;

  short* p0 = lds;
  short* p1 = lds + 16384;
  short* p2 = lds + 32768;

  // prologue: stage tile0 + tile1; drain tile0 only
  stage256(A,  lda, m0, 0,  p0,        tid);
  stage256(Bt, ldb, n0, 0,  p0 + 8192, tid);
  stage256(A,  lda, m0, 32, p1,        tid);
  stage256(Bt, ldb, n0, 32, p1 + 8192, tid);
  WAITV4();
  SBAR();

  for (int t = 0; t < nt; ++t) {
    short* cur = p0;
    if (t + 2 < nt) {
      const int kb2 = (t + 2) << 5;
      stage256(A,  lda, m0, kb2, p2,        tid);
      stage256(Bt, ldb, n0, kb2, p2 + 8192, tid);
    }

    bf16x8 Af[8], Bf[4];
#pragma unroll
    for (int m = 0; m < 8; ++m)
      Af[m] = lds_read8(cur, wr * 128 + m * 16 + lr, kg * 8);
#pragma unroll
    for (int n = 0; n < 4; ++n)
      Bf[n] = lds_read8(cur + 8192, wc * 64 + n * 16 + lr, kg * 8);

    __builtin_amdgcn_s_setprio(1);
#pragma unroll
    for (int m = 0; m < 8; ++m)
#pragma unroll
      for (int n = 0; n < 4; ++n)
        acc[m][n] = __builtin_amdgcn_mfma_f32_16x16x32_bf16(Af[m], Bf[n],
                                                            acc[m][n], 0, 0, 0);
    __builtin_amdgcn_s_setprio(0);

    if (t + 2 < nt) { WAITV4(); } else { WAITV0(); }
    SBAR();

    short* tmp = p0; p0 = p1; p1 = p2; p2 = tmp;   // rotate
  }
}

// ---------------------------------------------------------------------------
// 256x128 triple-buffer core. 8 waves (4x2), wave tile 64x64, acc[4][4].
// LDS 72KB = 3 buffers x (A 256x32 @0 + B 128x32 @8192 shorts; 12288 stride).
// Per tile: 3 loads/thread; end wait vmcnt(3) / tail vmcnt(0).
// ---------------------------------------------------------------------------
DEV void gemm_core_n128(const u16* __restrict__ A, int lda,
                        const u16* __restrict__ Bt, int ldb,
                        int m0, int n0, int K, short* lds, f32x4 (&acc)[4][4])
{
  const int tid = threadIdx.x;
  const int lane = tid & 63;
  const int wid = tid >> 6;
  const int wr = wid >> 1, wc = wid & 1;   // 4x2 wave grid
  const int lr = lane & 15, kg = lane >> 4;
  const int nt = K >> 5;

  short* p0 = lds;
  short* p1 = lds + 12288;
  short* p2 = lds + 24576;

  stage256(A,  lda, m0, 0,  p0,        tid);
  stage128(Bt, ldb, n0, 0,  p0 + 8192, tid);
  stage256(A,  lda, m0, 32, p1,        tid);
  stage128(Bt, ldb, n0, 32, p1 + 8192, tid);
  WAITV3();
  SBAR();

  for (int t = 0; t < nt; ++t) {
    short* cur = p0;
    if (t + 2 < nt) {
      const int kb2 = (t + 2) << 5;
      stage256(A,  lda, m0, kb2, p2,        tid);
      stage128(Bt, ldb, n0, kb2, p2 + 8192, tid);
    }

    bf16x8 Af[4], Bf[4];
#pragma unroll
    for (int m = 0; m < 4; ++m)
      Af[m] = lds_read8(cur, wr * 64 + m * 16 + lr, kg * 8);
#pragma unroll
    for (int n = 0; n < 4; ++n)
      Bf[n] = lds_read8(cur + 8192, wc * 64 + n * 16 + lr, kg * 8);

    __builtin_amdgcn_s_setprio(1);
#pragma unroll
    for (int m = 0; m < 4; ++m)
#pragma unroll
      for (int n = 0; n < 4; ++n)
        acc[m][n] = __builtin_amdgcn_mfma_f32_16x16x32_bf16(Af[m], Bf[n],
                                                            acc[m][n], 0, 0, 0);
    __builtin_amdgcn_s_setprio(0);

    if (t + 2 < nt) { WAITV3(); } else { WAITV0(); }
    SBAR();

    short* tmp = p0; p0 = p1; p1 = p2; p2 = tmp;
  }
}

// ---------------------------------------------------------------------------
// elementwise f32 -> bf16, two tensors in one launch (z selects)
// ---------------------------------------------------------------------------
__global__ __launch_bounds__(256) void cvt_bf16_kernel(const float* __restrict__ in0,
                                                       u16* __restrict__ out0,
                                                       const float* __restrict__ in1,
                                                       u16* __restrict__ out1)
{
  const float* in = blockIdx.y ? in1 : in0;
  u16* out = blockIdx.y ? out1 : out0;
  const size_t i = ((size_t)blockIdx.x * 256 + threadIdx.x) * 4;
  const float4 v = *(const float4*)(in + i);
  u16 o[4] = {f2bf(v.x), f2bf(v.y), f2bf(v.z), f2bf(v.w)};
  *(ushort4*)(out + i) = *(ushort4*)o;
}

// W [1024][1024] f32 -> WT [n][k] bf16; z selects {Wq->WqT, Wk->WkvT, Wv->WkvT+1M}
__global__ __launch_bounds__(256) void transpose_w_kernel(
    const float* __restrict__ Wq, const float* __restrict__ Wk,
    const float* __restrict__ Wv, u16* __restrict__ WqT, u16* __restrict__ WkvT)
{
  __shared__ float tile[32][33];
  const int z = blockIdx.z;
  const float* W = (z == 0) ? Wq : ((z == 1) ? Wk : Wv);
  u16* WT = (z == 0) ? WqT : (WkvT + (z == 2 ? (size_t)CD * CD : 0));
  const int tx = threadIdx.x, ty = threadIdx.y;   // 32 x 8
  const int bx = blockIdx.x, by = blockIdx.y;
#pragma unroll
  for (int i = 0; i < 4; ++i)
    tile[ty + i * 8][tx] = W[(size_t)(by * 32 + ty + i * 8) * CD + bx * 32 + tx];
  __syncthreads();
#pragma unroll
  for (int i = 0; i < 4; ++i)
    WT[(size_t)(bx * 32 + ty + i * 8) * CD + by * 32 + tx] =
        f2bf(tile[tx][ty + i * 8]);
}

// ---------------------------------------------------------------------------
// fused K|V GEMM: x2b [8192][1024] x WkvT [2048][1024]^T. grid 256.
// K-blocks (n0<CD): write K row-major. V-blocks: write Vt[b][d][n] via LDS
// transpose (2 passes, padded stride 264) + vsum partials via atomics.
// ---------------------------------------------------------------------------
__global__ __launch_bounds__(512, 2) void kv_kernel(
    const u16* __restrict__ x2b, const u16* __restrict__ WkvT,
    const float* __restrict__ bk, const float* __restrict__ bv,
    u16* __restrict__ Ko, u16* __restrict__ Vt, float* __restrict__ vsum)
{
  extern __shared__ char smem_raw[];
  short* lds = (short*)smem_raw;
  const int flat = blockIdx.y * 32 + blockIdx.x;      // nwg=256
  const int s = (flat & 7) * 32 + (flat >> 3);        // XCD swizzle
  const int bx = s & 31, by = s >> 5;
  const int m0 = bx * 256, n0 = by * 256;

  f32x4 acc[8][4] = {};
  gemm_core8(x2b, CD, WkvT, CD, m0, n0, CD, lds, acc);

  const int tid = threadIdx.x, lane = tid & 63, wid = tid >> 6;
  const int wr = wid >> 2, wc = wid & 3, lr = lane & 15, kg = lane >> 4;
  const bool isK = (n0 < CD);

  if (isK) {
#pragma unroll
    for (int mi = 0; mi < 8; ++mi)
#pragma unroll
      for (int ni = 0; ni < 4; ++ni) {
        const int col = n0 + wc * 64 + ni * 16 + lr;
        const float bcol = bk[col];
#pragma unroll
        for (int j = 0; j < 4; ++j) {
          const int row = m0 + wr * 128 + mi * 16 + kg * 4 + j;
          Ko[(size_t)row * CD + col] = f2bf(acc[mi][ni][j] + bcol);
        }
      }
  } else {
    const int c0 = n0 - CD;              // d-offset of this 256-col tile
    const int b = m0 >> 11;              // batch
    const int nwb = m0 & (CN - 1);       // n-offset within batch
    u16* ldsT = (u16*)smem_raw;          // [128][264] u16 = 67.6KB
    const int myp = wc >> 1;

    // vsum partials (bias included: wave covers 128 rows -> +128*bv[col])
#pragma unroll
    for (int ni = 0; ni < 4; ++ni) {
      const int col = c0 + wc * 64 + ni * 16 + lr;
      float sv = 128.0f * bv[col];
#pragma unroll
      for (int mi = 0; mi < 8; ++mi)
#pragma unroll
        for (int j = 0; j < 4; ++j)
          sv += acc[mi][ni][j];
      sv += __shfl_xor(sv, 16);
      sv += __shfl_xor(sv, 32);
      if (lane < 16) atomicAdd(&vsum[b * CD + col], sv);
    }

    // transpose via LDS, two 128-col passes
    for (int pass = 0; pass < 2; ++pass) {
      if (myp == pass) {
#pragma unroll
        for (int ni = 0; ni < 4; ++ni) {
          const int cl = (wc & 1) * 64 + ni * 16 + lr;   // 0..127
          const float bcol = bv[c0 + pass * 128 + cl];
#pragma unroll
          for (int mi = 0; mi < 8; ++mi)
#pragma unroll
            for (int j = 0; j < 4; ++j) {
              const int row = wr * 128 + mi * 16 + kg * 4 + j;  // 0..255
              ldsT[cl * 264 + row] = f2bf(acc[mi][ni][j] + bcol);
            }
        }
      }
      WAITL();
      SBAR();
      // coalesced copy-out: 128 d x 256 n bf16
#pragma unroll
      for (int i = 0; i < 8; ++i) {
        const int c = tid + i * 512;     // 0..4095
        const int dl = c >> 5;           // 0..127
        const int nk = c & 31;           // 0..31 (8-short chunks)
        bf16x8 vv = *(const bf16x8*)(ldsT + dl * 264 + nk * 8);
        *(bf16x8*)(Vt + ((size_t)b * CD + c0 + pass * 128 + dl) * CN +
                   nwb + nk * 8) = vv;
      }
      SBAR();
    }
  }
}

// ---------------------------------------------------------------------------
// Q GEMM: x1b x WqT, 256x128 tiles. grid 256.
// ---------------------------------------------------------------------------
__global__ __launch_bounds__(512, 2) void q_kernel(
    const u16* __restrict__ x1b, const u16* __restrict__ WqT,
    const float* __restrict__ bq, u16* __restrict__ Q)
{
  extern __shared__ char smem_raw[];
  short* lds = (short*)smem_raw;
  const int flat = blockIdx.y * 32 + blockIdx.x;      // nwg=256
  const int s = (flat & 7) * 32 + (flat >> 3);
  const int bx = s & 31, by = s >> 5;                 // 32 m-tiles, 8 n-tiles
  const int m0 = bx * 256, n0 = by * 128;

  f32x4 acc[4][4] = {};
  gemm_core_n128(x1b, CD, WqT, CD, m0, n0, CD, lds, acc);

  const int tid = threadIdx.x, lane = tid & 63, wid = tid >> 6;
  const int wr = wid >> 1, wc = wid & 1, lr = lane & 15, kg = lane >> 4;
#pragma unroll
  for (int mi = 0; mi < 4; ++mi)
#pragma unroll
    for (int ni = 0; ni < 4; ++ni) {
      const int col = n0 + wc * 64 + ni * 16 + lr;
      const float bcol = bq[col];
#pragma unroll
      for (int j = 0; j < 4; ++j) {
        const int row = m0 + wr * 64 + mi * 16 + kg * 4 + j;
        Q[(size_t)row * CD + col] = f2bf(acc[mi][ni][j] + bcol);
      }
    }
}

// ---------------------------------------------------------------------------
// P = exp(Q*K^T/32) (bf16), row sums l via atomics.  grid (8,8,4)
// ---------------------------------------------------------------------------
__global__ __launch_bounds__(512, 2) void scores_kernel(
    const u16* __restrict__ Q, const u16* __restrict__ Km,
    u16* __restrict__ P, float* __restrict__ lsum)
{
  extern __shared__ char smem_raw[];
  short* lds = (short*)smem_raw;
  const int flat = (blockIdx.z * 8 + blockIdx.y) * 8 + blockIdx.x;  // nwg=256
  const int s = (flat & 7) * 32 + (flat >> 3);
  const int bx = s & 7, by = (s >> 3) & 7, bz = s >> 6;
  const int m0 = bx * 256, n0 = by * 256;
  const u16* A  = Q  + (size_t)bz * CN * CD;
  const u16* Bt = Km + (size_t)bz * CN * CD;

  f32x4 acc[8][4] = {};
  gemm_core8(A, CD, Bt, CD, m0, n0, CD, lds, acc);

  const int tid = threadIdx.x, lane = tid & 63, wid = tid >> 6;
  const int wr = wid >> 2, wc = wid & 3, lr = lane & 15, kg = lane >> 4;
  u16* Pb = P + (size_t)bz * CN * CN;
  float* lb = lsum + (size_t)bz * CN;
  const float sc = 0.03125f * 1.4426950408889634f;
#pragma unroll
  for (int mi = 0; mi < 8; ++mi) {
    float rs[4] = {0.f, 0.f, 0.f, 0.f};
#pragma unroll
    for (int ni = 0; ni < 4; ++ni) {
      const int col = n0 + wc * 64 + ni * 16 + lr;
#pragma unroll
      for (int j = 0; j < 4; ++j) {
        const int row = m0 + wr * 128 + mi * 16 + kg * 4 + j;
        const float pv = exp2f(acc[mi][ni][j] * sc);
        Pb[(size_t)row * CN + col] = f2bf(pv);
        rs[j] += pv;
      }
    }
#pragma unroll
    for (int j = 0; j < 4; ++j) {
      float v = rs[j];
      v += __shfl_xor(v, 1);
      v += __shfl_xor(v, 2);
      v += __shfl_xor(v, 4);
      v += __shfl_xor(v, 8);
      if (lr == 0)
        atomicAdd(&lb[m0 + wr * 128 + mi * 16 + kg * 4 + j], v);
    }
  }
}

// ---------------------------------------------------------------------------
// out = (vsum - (P@V)/l) / (N-1)   (f32).  256x128 tiles, grid (8,8,4)=256.
// ---------------------------------------------------------------------------
__global__ __launch_bounds__(512, 2) void pv_kernel(
    const u16* __restrict__ P, const u16* __restrict__ Vt,
    const float* __restrict__ lsum, const float* __restrict__ vsum,
    float* __restrict__ out)
{
  extern __shared__ char smem_raw[];
  short* lds = (short*)smem_raw;
  const int flat = (blockIdx.z * 8 + blockIdx.y) * 8 + blockIdx.x;  // nwg=256
  const int s = (flat & 7) * 32 + (flat >> 3);
  const int bx = s & 7, by = (s >> 3) & 7, bz = s >> 6;
  const int m0 = bx * 256, n0 = by * 128;
  const u16* A  = P  + (size_t)bz * CN * CN;   // [2048][2048]
  const u16* Bt = Vt + (size_t)bz * CD * CN;   // [1024][2048]

  f32x4 acc[4][4] = {};
  gemm_core_n128(A, CN, Bt, CN, m0, n0, CN, lds, acc);

  const int tid = threadIdx.x, lane = tid & 63, wid = tid >> 6;
  const int wr = wid >> 1, wc = wid & 1, lr = lane & 15, kg = lane >> 4;
  const float inv_nm1 = 1.0f / (float)(CN - 1);
#pragma unroll
  for (int mi = 0; mi < 4; ++mi)
#pragma unroll
    for (int j = 0; j < 4; ++j) {
      const int row = m0 + wr * 64 + mi * 16 + kg * 4 + j;
      const float rl = 1.0f / lsum[(size_t)bz * CN + row];
#pragma unroll
      for (int ni = 0; ni < 4; ++ni) {
        const int col = n0 + wc * 64 + ni * 16 + lr;
        const float ctx = (vsum[bz * CD + col] - acc[mi][ni][j] * rl) * inv_nm1;
        out[(size_t)(bz * CN + row) * CD + col] = ctx;
      }
    }
}

// in-place LayerNorm + ReLU per row of 1024
__global__ __launch_bounds__(256) void ln_relu_kernel(float* __restrict__ io,
                                                      const float* __restrict__ gamma,
                                                      const float* __restrict__ beta)
{
  float* x = io + (size_t)blockIdx.x * CD;
  const int t = threadIdx.x;
  float4 v = ((const float4*)x)[t];
  float s = v.x + v.y + v.z + v.w;
  float q = v.x * v.x + v.y * v.y + v.z * v.z + v.w * v.w;
#pragma unroll
  for (int off = 1; off < 64; off <<= 1) {
    s += __shfl_xor(s, off);
    q += __shfl_xor(q, off);
  }
  __shared__ float ss[4], qq[4];
  const int w = t >> 6, lane = t & 63;
  if (lane == 0) { ss[w] = s; qq[w] = q; }
  __syncthreads();
  s = ss[0] + ss[1] + ss[2] + ss[3];
  q = qq[0] + qq[1] + qq[2] + qq[3];
  const float mean = s * (1.0f / CD);
  const float var  = q * (1.0f / CD) - mean * mean;
  const float rstd = rsqrtf(var + 1e-5f);
  const float4 g  = ((const float4*)gamma)[t];
  const float4 bb = ((const float4*)beta)[t];
  v.x = fmaxf(0.f, (v.x - mean) * rstd * g.x + bb.x);
  v.y = fmaxf(0.f, (v.y - mean) * rstd * g.y + bb.y);
  v.z = fmaxf(0.f, (v.z - mean) * rstd * g.z + bb.z);
  v.w = fmaxf(0.f, (v.w - mean) * rstd * g.w + bb.w);
  ((float4*)x)[t] = v;
}

// ---------------------------------------------------------------------------
extern "C" void kernel_launch(void* const* d_in, const int* in_sizes, int n_in,
                              void* d_out, int out_size, void* d_ws, size_t ws_size,
                              hipStream_t stream)
{
  (void)in_sizes; (void)n_in; (void)out_size; (void)ws_size;
  const float* x1    = (const float*)d_in[0];
  const float* x2    = (const float*)d_in[1];
  const float* Wq    = (const float*)d_in[2];
  const float* bq    = (const float*)d_in[3];
  const float* Wk    = (const float*)d_in[4];
  const float* bk    = (const float*)d_in[5];
  const float* Wv    = (const float*)d_in[6];
  const float* bv    = (const float*)d_in[7];
  const float* gamma = (const float*)d_in[8];
  const float* beta  = (const float*)d_in[9];
  float* out = (float*)d_out;

  const int LDS_BIG = 98304, LDS_MID = 73728;
  hipFuncSetAttribute((const void*)kv_kernel,
                      hipFuncAttributeMaxDynamicSharedMemorySize, LDS_BIG);
  hipFuncSetAttribute((const void*)scores_kernel,
                      hipFuncAttributeMaxDynamicSharedMemorySize, LDS_BIG);
  hipFuncSetAttribute((const void*)q_kernel,
                      hipFuncAttributeMaxDynamicSharedMemorySize, LDS_MID);
  hipFuncSetAttribute((const void*)pv_kernel,
                      hipFuncAttributeMaxDynamicSharedMemorySize, LDS_MID);

  char* p = (char*)d_ws;
  auto alloc = [&](size_t bytes) -> char* {
    char* r = p;
    p += (bytes + 255) & ~(size_t)255;
    return r;
  };
  u16* x1b   = (u16*)alloc((size_t)CM * CD * 2);
  u16* x2b   = (u16*)alloc((size_t)CM * CD * 2);
  u16* WqT   = (u16*)alloc((size_t)CD * CD * 2);
  u16* WkvT  = (u16*)alloc((size_t)2 * CD * CD * 2);
  u16* Qb    = (u16*)alloc((size_t)CM * CD * 2);
  u16* Kb    = (u16*)alloc((size_t)CM * CD * 2);
  u16* Vt    = (u16*)alloc((size_t)CM * CD * 2);
  u16* Pp    = (u16*)alloc((size_t)CB * CN * CN * 2);
  float* ls  = (float*)alloc((size_t)CB * CN * 4);
  float* vs  = (float*)alloc((size_t)CB * CD * 4);

  hipMemsetAsync(ls, 0, (size_t)CB * CN * 4, stream);
  hipMemsetAsync(vs, 0, (size_t)CB * CD * 4, stream);

  // f32 -> bf16 inputs (one launch)
  {
    dim3 g(CM * CD / 1024, 2);
    cvt_bf16_kernel<<<g, 256, 0, stream>>>(x1, x1b, x2, x2b);
  }

  // W transposes (one launch)
  {
    dim3 g(32, 32, 3), blk(32, 8);
    transpose_w_kernel<<<g, blk, 0, stream>>>(Wq, Wk, Wv, WqT, WkvT);
  }

  // fused K|V projection: K row-major + Vt + vsum (256 blocks)
  {
    dim3 g(32, 8);
    kv_kernel<<<g, 512, LDS_BIG, stream>>>(x2b, WkvT, bk, bv, Kb, Vt, vs);
  }

  // Q projection (256 blocks, 256x128 tiles)
  {
    dim3 g(32, 8);
    q_kernel<<<g, 512, LDS_MID, stream>>>(x1b, WqT, bq, Qb);
  }

  // P = exp(QK^T/32), l = rowsum(P)
  {
    dim3 g(8, 8, CB);
    scores_kernel<<<g, 512, LDS_BIG, stream>>>(Qb, Kb, Pp, ls);
  }

  // out = (vsum - P@V / l) / (N-1)   (256 blocks, 256x128 tiles)
  {
    dim3 g(8, 8, CB);
    pv_kernel<<<g, 512, LDS_MID, stream>>>(Pp, Vt, ls, vs, out);
  }

  // LayerNorm + ReLU in place
  ln_relu_kernel<<<CM, 256, 0, stream>>>(out, gamma, beta);
}

// Round 8
// 159.769 us; speedup vs baseline: 1.2574x; 1.2574x over previous
//
#include <hip/hip_runtime.h>

typedef __attribute__((ext_vector_type(8))) short bf16x8;
typedef __attribute__((ext_vector_type(4))) float f32x4;
typedef __attribute__((ext_vector_type(4))) int   i32x4;
typedef __attribute__((ext_vector_type(8))) int   i32x8;
typedef unsigned short u16;
typedef unsigned int u32;
typedef unsigned char u8;

#define DEV static __device__ __forceinline__

// problem sizes (fixed by the reference)
#define CB 4
#define CN 2048
#define CD 1024
#define CM 8192   // CB*CN

DEV u16 f2bf(float f) {
  u32 u = __float_as_uint(f);
  u = (u + 0x7FFFu + ((u >> 16) & 1u)) >> 16;
  return (u16)u;
}
DEV float bf2f(u16 h) { return __uint_as_float(((u32)h) << 16); }

DEV u8 f2fp8(float f) {
  return (u8)(__builtin_amdgcn_cvt_pk_fp8_f32(f, 0.f, 0, false) & 0xff);
}

#define GLD16(gsrc, ldst)                                                        \
  __builtin_amdgcn_global_load_lds(                                              \
      (const __attribute__((address_space(1))) void*)(gsrc),                     \
      (__attribute__((address_space(3))) void*)(ldst), 16, 0, 0)

#define SBAR()  asm volatile("s_barrier" ::: "memory")
#define WAITL() asm volatile("s_waitcnt lgkmcnt(0)" ::: "memory")
#define WAITV0() asm volatile("s_waitcnt vmcnt(0)" ::: "memory")

// unit-scale (E8M0=127) fp8xfp8 K=128 MFMA
#define MFMA_F8(a, b, c)                                                         \
  __builtin_amdgcn_mfma_scale_f32_16x16x128_f8f6f4((a), (b), (c), 0, 0, 0, 127,  \
                                                   0, 127)

// ---------------------------------------------------------------------------
// bf16 LDS half-tile = [128 rows][64 k] bf16, 128B rows, XOR-swizzled:
//   byte ^= ((byte>>7)&7)<<4   (proven 0-conflict layout, R6)
// ---------------------------------------------------------------------------
DEV bf16x8 lds_read8(const short* half, int row, int kelem) {
  int b = row * 128 + kelem * 2;
  b ^= ((b >> 7) & 7) << 4;
  return *(const bf16x8*)((const char*)half + b);
}

DEV void stage_half(const u16* __restrict__ g, int ld, int row0, int kb,
                    short* lds_half, int tid) {
#pragma unroll
  for (int s = 0; s < 2; ++s) {
    const int c = tid + s * 512;                // 16B chunk 0..1023
    const int lo = (c ^ ((c >> 3) & 7)) & 7;    // intra-row source chunk
    GLD16(g + (size_t)(row0 + (c >> 3)) * ld + kb + lo * 8,
          (char*)lds_half + c * 16);
  }
}

// ---------------------------------------------------------------------------
// fp8 LDS tiles: [rows][128 bytes] - identical 128B-row bank geometry, same
// swizzle. Per-lane fragment = 32 bytes (two b128 reads at +0,+16).
// ---------------------------------------------------------------------------
DEV i32x8 lds_read_f8(const char* region, int row, int kbyte) {
  int b0 = row * 128 + kbyte;      b0 ^= ((b0 >> 7) & 7) << 4;
  int b1 = row * 128 + kbyte + 16; b1 ^= ((b1 >> 7) & 7) << 4;
  i32x4 lo = *(const i32x4*)(region + b0);
  i32x4 hi = *(const i32x4*)(region + b1);
  i32x8 r;
  r[0] = lo[0]; r[1] = lo[1]; r[2] = lo[2]; r[3] = lo[3];
  r[4] = hi[0]; r[5] = hi[1]; r[6] = hi[2]; r[7] = hi[3];
  return r;
}

// stage fp8 [256 rows][128B] tile (32KB): 2048 chunks, 4/thread
DEV void stage_f8_256(const u8* __restrict__ g, int ld, int row0, int kb,
                      char* dst, int tid) {
#pragma unroll
  for (int s = 0; s < 4; ++s) {
    const int c = tid + s * 512;
    const int row = c >> 3, sl = c & 7;
    const int lo = sl ^ (row & 7);
    GLD16(g + (size_t)(row0 + row) * ld + kb + lo * 16, dst + c * 16);
  }
}
// stage fp8 [128 rows][128B] tile (16KB): 1024 chunks, 2/thread
DEV void stage_f8_128(const u8* __restrict__ g, int ld, int row0, int kb,
                      char* dst, int tid) {
#pragma unroll
  for (int s = 0; s < 2; ++s) {
    const int c = tid + s * 512;
    const int row = c >> 3, sl = c & 7;
    const int lo = sl ^ (row & 7);
    GLD16(g + (size_t)(row0 + row) * ld + kb + lo * 16, dst + c * 16);
  }
}

// ---------------------------------------------------------------------------
// bf16 256x256 single-barrier core (R6, proven). 8 waves (2x4), acc[8][4].
// LDS 128KB: per buffer A0@0, A1@8192, B0@16384, B1@24576 (shorts).
// ---------------------------------------------------------------------------
template <int MH, int NH>
DEV void mfma_quad(f32x4 (&acc)[8][4], const bf16x8 (&Af)[4][2],
                   const bf16x8 (&Bfh)[2][2]) {
#pragma unroll
  for (int mm = 0; mm < 4; ++mm)
#pragma unroll
    for (int nn = 0; nn < 2; ++nn)
#pragma unroll
      for (int ks = 0; ks < 2; ++ks)
        acc[MH * 4 + mm][NH * 2 + nn] = __builtin_amdgcn_mfma_f32_16x16x32_bf16(
            Af[mm][ks], Bfh[nn][ks], acc[MH * 4 + mm][NH * 2 + nn], 0, 0, 0);
}

DEV void gemm_core8(const u16* __restrict__ A, int lda,
                    const u16* __restrict__ Bt, int ldb,
                    int m0, int n0, int K, short* lds, f32x4 (&acc)[8][4])
{
  const int tid = threadIdx.x;
  const int lane = tid & 63;
  const int wid = tid >> 6;
  const int wr = wid >> 2, wc = wid & 3;
  const int lr = lane & 15, kg = lane >> 4;
  const int nt = K >> 6;

  short* buf0 = lds;
  short* buf1 = lds + 32768;

  stage_half(A,  lda, m0,       0, buf0,         tid);
  stage_half(A,  lda, m0 + 128, 0, buf0 + 8192,  tid);
  stage_half(Bt, ldb, n0,       0, buf0 + 16384, tid);
  stage_half(Bt, ldb, n0 + 128, 0, buf0 + 24576, tid);
  WAITV0();
  SBAR();

  bf16x8 Af[4][2], Bf[2][2][2];

  for (int t = 0; t < nt; ++t) {
    short* cur = (t & 1) ? buf1 : buf0;
    short* nxt = (t & 1) ? buf0 : buf1;
    const short* aHalf = cur + wr * 8192;
    const short* bHalf = cur + 16384 + (wc >> 1) * 8192;
    const int bl0 = (wc & 1) * 64;
    const int kb1 = (t + 1) << 6;

    if (t + 1 < nt) {
      stage_half(A,  lda, m0,       kb1, nxt,         tid);
      stage_half(A,  lda, m0 + 128, kb1, nxt + 8192,  tid);
      stage_half(Bt, ldb, n0,       kb1, nxt + 16384, tid);
      stage_half(Bt, ldb, n0 + 128, kb1, nxt + 24576, tid);
    }

#pragma unroll
    for (int m = 0; m < 4; ++m)
#pragma unroll
      for (int ks = 0; ks < 2; ++ks)
        Af[m][ks] = lds_read8(aHalf, m * 16 + lr, ks * 32 + kg * 8);
#pragma unroll
    for (int n = 0; n < 2; ++n)
#pragma unroll
      for (int ks = 0; ks < 2; ++ks) {
        Bf[0][n][ks] = lds_read8(bHalf, bl0 + n * 16 + lr, ks * 32 + kg * 8);
        Bf[1][n][ks] = lds_read8(bHalf, bl0 + 32 + n * 16 + lr, ks * 32 + kg * 8);
      }

    __builtin_amdgcn_s_setprio(1);
    mfma_quad<0, 0>(acc, Af, Bf[0]);
    mfma_quad<0, 1>(acc, Af, Bf[1]);
    __builtin_amdgcn_s_setprio(0);

#pragma unroll
    for (int m = 0; m < 4; ++m)
#pragma unroll
      for (int ks = 0; ks < 2; ++ks)
        Af[m][ks] = lds_read8(aHalf, 64 + m * 16 + lr, ks * 32 + kg * 8);

    __builtin_amdgcn_s_setprio(1);
    mfma_quad<1, 1>(acc, Af, Bf[1]);
    mfma_quad<1, 0>(acc, Af, Bf[0]);
    __builtin_amdgcn_s_setprio(0);

    WAITV0();
    SBAR();
  }
}

// ---------------------------------------------------------------------------
// bf16 256x128 single-barrier core (R6, proven). 8 waves (4x2), acc[4][4].
// LDS 96KB: per buffer A0@0, A1@8192, B@16384 (shorts, 24576/buffer).
// ---------------------------------------------------------------------------
template <int MH, int NH>
DEV void mfma_oct(f32x4 (&acc)[4][4], const bf16x8 (&Af)[2][2],
                  const bf16x8 (&Bfh)[2][2]) {
#pragma unroll
  for (int mm = 0; mm < 2; ++mm)
#pragma unroll
    for (int nn = 0; nn < 2; ++nn)
#pragma unroll
      for (int ks = 0; ks < 2; ++ks)
        acc[MH * 2 + mm][NH * 2 + nn] = __builtin_amdgcn_mfma_f32_16x16x32_bf16(
            Af[mm][ks], Bfh[nn][ks], acc[MH * 2 + mm][NH * 2 + nn], 0, 0, 0);
}

DEV void gemm_core_n128(const u16* __restrict__ A, int lda,
                        const u16* __restrict__ Bt, int ldb,
                        int m0, int n0, int K, short* lds, f32x4 (&acc)[4][4])
{
  const int tid = threadIdx.x;
  const int lane = tid & 63;
  const int wid = tid >> 6;
  const int wr = wid >> 1, wc = wid & 1;   // 4x2 wave grid
  const int lr = lane & 15, kg = lane >> 4;
  const int nt = K >> 6;

  short* buf0 = lds;
  short* buf1 = lds + 24576;

  stage_half(A,  lda, m0,       0, buf0,         tid);
  stage_half(A,  lda, m0 + 128, 0, buf0 + 8192,  tid);
  stage_half(Bt, ldb, n0,       0, buf0 + 16384, tid);
  WAITV0();
  SBAR();

  bf16x8 AfA[2][2], AfB[2][2], Bf[2][2][2];

  for (int t = 0; t < nt; ++t) {
    short* cur = (t & 1) ? buf1 : buf0;
    short* nxt = (t & 1) ? buf0 : buf1;
    const short* aHalf = cur + (wr >> 1) * 8192;
    const short* bHalf = cur + 16384;
    const int ar0 = (wr & 1) * 64;
    const int bc0 = wc * 64;
    const int kb1 = (t + 1) << 6;

    if (t + 1 < nt) {
      stage_half(A,  lda, m0,       kb1, nxt,         tid);
      stage_half(A,  lda, m0 + 128, kb1, nxt + 8192,  tid);
      stage_half(Bt, ldb, n0,       kb1, nxt + 16384, tid);
    }

#pragma unroll
    for (int m = 0; m < 2; ++m)
#pragma unroll
      for (int ks = 0; ks < 2; ++ks) {
        AfA[m][ks] = lds_read8(aHalf, ar0 + m * 16 + lr, ks * 32 + kg * 8);
        AfB[m][ks] = lds_read8(aHalf, ar0 + 32 + m * 16 + lr, ks * 32 + kg * 8);
      }
#pragma unroll
    for (int n = 0; n < 2; ++n)
#pragma unroll
      for (int ks = 0; ks < 2; ++ks) {
        Bf[0][n][ks] = lds_read8(bHalf, bc0 + n * 16 + lr, ks * 32 + kg * 8);
        Bf[1][n][ks] = lds_read8(bHalf, bc0 + 32 + n * 16 + lr, ks * 32 + kg * 8);
      }

    __builtin_amdgcn_s_setprio(1);
    mfma_oct<0, 0>(acc, AfA, Bf[0]);
    mfma_oct<0, 1>(acc, AfA, Bf[1]);
    mfma_oct<1, 1>(acc, AfB, Bf[1]);
    mfma_oct<1, 0>(acc, AfB, Bf[0]);
    __builtin_amdgcn_s_setprio(0);

    WAITV0();
    SBAR();
  }
}

// ---------------------------------------------------------------------------
// fp8 256x256 core (scores): same single-barrier protocol, K-tile = 128.
// LDS 128KB: per buffer A[256][128B]@0, B[256][128B]@32768 (bytes).
// ---------------------------------------------------------------------------
DEV void gemm_core_f8(const u8* __restrict__ A, int lda,
                      const u8* __restrict__ Bt, int ldb,
                      int m0, int n0, int K, char* lds, f32x4 (&acc)[8][4])
{
  const int tid = threadIdx.x;
  const int lane = tid & 63;
  const int wid = tid >> 6;
  const int wr = wid >> 2, wc = wid & 3;
  const int lr = lane & 15, kg = lane >> 4;
  const int nt = K >> 7;

  char* buf0 = lds;
  char* buf1 = lds + 65536;

  stage_f8_256(A,  lda, m0, 0, buf0,         tid);
  stage_f8_256(Bt, ldb, n0, 0, buf0 + 32768, tid);
  WAITV0();
  SBAR();

  for (int t = 0; t < nt; ++t) {
    char* cur = (t & 1) ? buf1 : buf0;
    char* nxt = (t & 1) ? buf0 : buf1;
    const int kb1 = (t + 1) << 7;

    if (t + 1 < nt) {
      stage_f8_256(A,  lda, m0, kb1, nxt,         tid);
      stage_f8_256(Bt, ldb, n0, kb1, nxt + 32768, tid);
    }

    i32x8 Bf[4];
#pragma unroll
    for (int n = 0; n < 4; ++n)
      Bf[n] = lds_read_f8(cur + 32768, wc * 64 + n * 16 + lr, kg * 32);

#pragma unroll
    for (int half = 0; half < 2; ++half) {
      i32x8 Af[4];
#pragma unroll
      for (int m = 0; m < 4; ++m)
        Af[m] = lds_read_f8(cur, wr * 128 + half * 64 + m * 16 + lr, kg * 32);
      __builtin_amdgcn_s_setprio(1);
#pragma unroll
      for (int m = 0; m < 4; ++m)
#pragma unroll
        for (int n = 0; n < 4; ++n)
          acc[half * 4 + m][n] = MFMA_F8(Af[m], Bf[n], acc[half * 4 + m][n]);
      __builtin_amdgcn_s_setprio(0);
    }

    WAITV0();
    SBAR();
  }
}

// ---------------------------------------------------------------------------
// fp8 256x128 core (pv): LDS 96KB: per buffer A[256][128B]@0, B[128][128B]
// @32768; buffer stride 49152.
// ---------------------------------------------------------------------------
DEV void gemm_core_f8_n128(const u8* __restrict__ A, int lda,
                           const u8* __restrict__ Bt, int ldb,
                           int m0, int n0, int K, char* lds, f32x4 (&acc)[4][4])
{
  const int tid = threadIdx.x;
  const int lane = tid & 63;
  const int wid = tid >> 6;
  const int wr = wid >> 1, wc = wid & 1;
  const int lr = lane & 15, kg = lane >> 4;
  const int nt = K >> 7;

  char* buf0 = lds;
  char* buf1 = lds + 49152;

  stage_f8_256(A,  lda, m0, 0, buf0,         tid);
  stage_f8_128(Bt, ldb, n0, 0, buf0 + 32768, tid);
  WAITV0();
  SBAR();

  for (int t = 0; t < nt; ++t) {
    char* cur = (t & 1) ? buf1 : buf0;
    char* nxt = (t & 1) ? buf0 : buf1;
    const int kb1 = (t + 1) << 7;

    if (t + 1 < nt) {
      stage_f8_256(A,  lda, m0, kb1, nxt,         tid);
      stage_f8_128(Bt, ldb, n0, kb1, nxt + 32768, tid);
    }

    i32x8 Af[4], Bf[4];
#pragma unroll
    for (int m = 0; m < 4; ++m)
      Af[m] = lds_read_f8(cur, wr * 64 + m * 16 + lr, kg * 32);
#pragma unroll
    for (int n = 0; n < 4; ++n)
      Bf[n] = lds_read_f8(cur + 32768, wc * 64 + n * 16 + lr, kg * 32);

    __builtin_amdgcn_s_setprio(1);
#pragma unroll
    for (int m = 0; m < 4; ++m)
#pragma unroll
      for (int n = 0; n < 4; ++n)
        acc[m][n] = MFMA_F8(Af[m], Bf[n], acc[m][n]);
    __builtin_amdgcn_s_setprio(0);

    WAITV0();
    SBAR();
  }
}

// ---------------------------------------------------------------------------
// elementwise f32 -> bf16, two tensors in one launch
// ---------------------------------------------------------------------------
__global__ __launch_bounds__(256) void cvt_bf16_kernel(const float* __restrict__ in0,
                                                       u16* __restrict__ out0,
                                                       const float* __restrict__ in1,
                                                       u16* __restrict__ out1)
{
  const float* in = blockIdx.y ? in1 : in0;
  u16* out = blockIdx.y ? out1 : out0;
  const size_t i = ((size_t)blockIdx.x * 256 + threadIdx.x) * 4;
  const float4 v = *(const float4*)(in + i);
  u16 o[4] = {f2bf(v.x), f2bf(v.y), f2bf(v.z), f2bf(v.w)};
  *(ushort4*)(out + i) = *(ushort4*)o;
}

// W [1024][1024] f32 -> WT [n][k] bf16; z selects {Wq->WqT, Wk->WkvT, Wv->WkvT+1M}
__global__ __launch_bounds__(256) void transpose_w_kernel(
    const float* __restrict__ Wq, const float* __restrict__ Wk,
    const float* __restrict__ Wv, u16* __restrict__ WqT, u16* __restrict__ WkvT)
{
  __shared__ float tile[32][33];
  const int z = blockIdx.z;
  const float* W = (z == 0) ? Wq : ((z == 1) ? Wk : Wv);
  u16* WT = (z == 0) ? WqT : (WkvT + (z == 2 ? (size_t)CD * CD : 0));
  const int tx = threadIdx.x, ty = threadIdx.y;   // 32 x 8
  const int bx = blockIdx.x, by = blockIdx.y;
#pragma unroll
  for (int i = 0; i < 4; ++i)
    tile[ty + i * 8][tx] = W[(size_t)(by * 32 + ty + i * 8) * CD + bx * 32 + tx];
  __syncthreads();
#pragma unroll
  for (int i = 0; i < 4; ++i)
    WT[(size_t)(bx * 32 + ty + i * 8) * CD + by * 32 + tx] =
        f2bf(tile[tx][ty + i * 8]);
}

// ---------------------------------------------------------------------------
// fused K|V GEMM (bf16 core). K-blocks: write K fp8. V-blocks: write Vt fp8
// via LDS transpose + vsum (f32, exact) via atomics.
// ---------------------------------------------------------------------------
__global__ __launch_bounds__(512, 2) void kv_kernel(
    const u16* __restrict__ x2b, const u16* __restrict__ WkvT,
    const float* __restrict__ bk, const float* __restrict__ bv,
    u8* __restrict__ Ko, u8* __restrict__ Vt, float* __restrict__ vsum)
{
  extern __shared__ char smem_raw[];
  short* lds = (short*)smem_raw;
  const int flat = blockIdx.y * 32 + blockIdx.x;      // nwg=256
  const int s = (flat & 7) * 32 + (flat >> 3);        // XCD swizzle
  const int bx = s & 31, by = s >> 5;
  const int m0 = bx * 256, n0 = by * 256;

  f32x4 acc[8][4] = {};
  gemm_core8(x2b, CD, WkvT, CD, m0, n0, CD, lds, acc);

  const int tid = threadIdx.x, lane = tid & 63, wid = tid >> 6;
  const int wr = wid >> 2, wc = wid & 3, lr = lane & 15, kg = lane >> 4;
  const bool isK = (n0 < CD);

  if (isK) {
#pragma unroll
    for (int mi = 0; mi < 8; ++mi)
#pragma unroll
      for (int ni = 0; ni < 4; ++ni) {
        const int col = n0 + wc * 64 + ni * 16 + lr;
        const float bcol = bk[col];
#pragma unroll
        for (int j = 0; j < 4; ++j) {
          const int row = m0 + wr * 128 + mi * 16 + kg * 4 + j;
          Ko[(size_t)row * CD + col] = f2fp8(acc[mi][ni][j] + bcol);
        }
      }
  } else {
    const int c0 = n0 - CD;              // d-offset of this 256-col tile
    const int b = m0 >> 11;              // batch
    const int nwb = m0 & (CN - 1);       // n-offset within batch
    u8* ldsT = (u8*)smem_raw;            // [128][272] u8 = 34.8KB
    const int myp = wc >> 1;

    // vsum partials (exact f32; bias included per 128-row wave)
#pragma unroll
    for (int ni = 0; ni < 4; ++ni) {
      const int col = c0 + wc * 64 + ni * 16 + lr;
      float sv = 128.0f * bv[col];
#pragma unroll
      for (int mi = 0; mi < 8; ++mi)
#pragma unroll
        for (int j = 0; j < 4; ++j)
          sv += acc[mi][ni][j];
      sv += __shfl_xor(sv, 16);
      sv += __shfl_xor(sv, 32);
      if (lane < 16) atomicAdd(&vsum[b * CD + col], sv);
    }

    // fp8 transpose via LDS, two 128-col passes
    for (int pass = 0; pass < 2; ++pass) {
      if (myp == pass) {
#pragma unroll
        for (int ni = 0; ni < 4; ++ni) {
          const int cl = (wc & 1) * 64 + ni * 16 + lr;   // 0..127
          const float bcol = bv[c0 + pass * 128 + cl];
#pragma unroll
          for (int mi = 0; mi < 8; ++mi) {
            const int rowb = wr * 128 + mi * 16 + kg * 4;  // 4-aligned
            const int p01 = __builtin_amdgcn_cvt_pk_fp8_f32(
                acc[mi][ni][0] + bcol, acc[mi][ni][1] + bcol, 0, false);
            const int p23 = __builtin_amdgcn_cvt_pk_fp8_f32(
                acc[mi][ni][2] + bcol, acc[mi][ni][3] + bcol, 0, false);
            *(u32*)(ldsT + cl * 272 + rowb) =
                (u32)(p01 & 0xffff) | ((u32)(p23 & 0xffff) << 16);
          }
        }
      }
      WAITL();
      SBAR();
      // coalesced copy-out: 128 d x 256 n fp8 = 2048 16B chunks
#pragma unroll
      for (int i = 0; i < 4; ++i) {
        const int c = tid + i * 512;     // 0..2047
        const int dl = c >> 4;           // 0..127
        const int nk = c & 15;           // 16B chunk (16 n)
        i32x4 vv = *(const i32x4*)(ldsT + dl * 272 + nk * 16);
        *(i32x4*)(Vt + ((size_t)b * CD + c0 + pass * 128 + dl) * CN +
                  nwb + nk * 16) = vv;
      }
      SBAR();
    }
  }
}

// ---------------------------------------------------------------------------
// Q GEMM (bf16 core), writes Q fp8. grid 256.
// ---------------------------------------------------------------------------
__global__ __launch_bounds__(512, 2) void q_kernel(
    const u16* __restrict__ x1b, const u16* __restrict__ WqT,
    const float* __restrict__ bq, u8* __restrict__ Q)
{
  extern __shared__ char smem_raw[];
  short* lds = (short*)smem_raw;
  const int flat = blockIdx.y * 32 + blockIdx.x;      // nwg=256
  const int s = (flat & 7) * 32 + (flat >> 3);
  const int bx = s & 31, by = s >> 5;                 // 32 m-tiles, 8 n-tiles
  const int m0 = bx * 256, n0 = by * 128;

  f32x4 acc[4][4] = {};
  gemm_core_n128(x1b, CD, WqT, CD, m0, n0, CD, lds, acc);

  const int tid = threadIdx.x, lane = tid & 63, wid = tid >> 6;
  const int wr = wid >> 1, wc = wid & 1, lr = lane & 15, kg = lane >> 4;
#pragma unroll
  for (int mi = 0; mi < 4; ++mi)
#pragma unroll
    for (int ni = 0; ni < 4; ++ni) {
      const int col = n0 + wc * 64 + ni * 16 + lr;
      const float bcol = bq[col];
#pragma unroll
      for (int j = 0; j < 4; ++j) {
        const int row = m0 + wr * 64 + mi * 16 + kg * 4 + j;
        Q[(size_t)row * CD + col] = f2fp8(acc[mi][ni][j] + bcol);
      }
    }
}

// ---------------------------------------------------------------------------
// P/4 = exp(Q*K^T/32)/4 (fp8), row sums l (f32) via atomics. grid (8,8,4)
// ---------------------------------------------------------------------------
__global__ __launch_bounds__(512, 2) void scores_kernel(
    const u8* __restrict__ Q, const u8* __restrict__ Km,
    u8* __restrict__ P, float* __restrict__ lsum)
{
  extern __shared__ char smem_raw[];
  const int flat = (blockIdx.z * 8 + blockIdx.y) * 8 + blockIdx.x;  // nwg=256
  const int s = (flat & 7) * 32 + (flat >> 3);
  const int bx = s & 7, by = (s >> 3) & 7, bz = s >> 6;
  const int m0 = bx * 256, n0 = by * 256;
  const u8* A  = Q  + (size_t)bz * CN * CD;
  const u8* Bt = Km + (size_t)bz * CN * CD;

  f32x4 acc[8][4] = {};
  gemm_core_f8(A, CD, Bt, CD, m0, n0, CD, smem_raw, acc);

  const int tid = threadIdx.x, lane = tid & 63, wid = tid >> 6;
  const int wr = wid >> 2, wc = wid & 3, lr = lane & 15, kg = lane >> 4;
  u8* Pb = P + (size_t)bz * CN * CN;
  float* lb = lsum + (size_t)bz * CN;
  const float sc = 0.03125f * 1.4426950408889634f;
#pragma unroll
  for (int mi = 0; mi < 8; ++mi) {
    float rs[4] = {0.f, 0.f, 0.f, 0.f};
#pragma unroll
    for (int ni = 0; ni < 4; ++ni) {
      const int col = n0 + wc * 64 + ni * 16 + lr;
#pragma unroll
      for (int j = 0; j < 4; ++j) {
        const int row = m0 + wr * 128 + mi * 16 + kg * 4 + j;
        const float pv = exp2f(acc[mi][ni][j] * sc);
        rs[j] += pv;
        Pb[(size_t)row * CN + col] = f2fp8(pv * 0.25f);
      }
    }
#pragma unroll
    for (int j = 0; j < 4; ++j) {
      float v = rs[j];
      v += __shfl_xor(v, 1);
      v += __shfl_xor(v, 2);
      v += __shfl_xor(v, 4);
      v += __shfl_xor(v, 8);
      if (lr == 0)
        atomicAdd(&lb[m0 + wr * 128 + mi * 16 + kg * 4 + j], v);
    }
  }
}

// ---------------------------------------------------------------------------
// out = (vsum - 4*(P/4 @ V)/l) / (N-1)   (f32). grid (8,8,4)=256.
// ---------------------------------------------------------------------------
__global__ __launch_bounds__(512, 2) void pv_kernel(
    const u8* __restrict__ P, const u8* __restrict__ Vt,
    const float* __restrict__ lsum, const float* __restrict__ vsum,
    float* __restrict__ out)
{
  extern __shared__ char smem_raw[];
  const int flat = (blockIdx.z * 8 + blockIdx.y) * 8 + blockIdx.x;  // nwg=256
  const int s = (flat & 7) * 32 + (flat >> 3);
  const int bx = s & 7, by = (s >> 3) & 7, bz = s >> 6;
  const int m0 = bx * 256, n0 = by * 128;
  const u8* A  = P  + (size_t)bz * CN * CN;   // [2048][2048] fp8
  const u8* Bt = Vt + (size_t)bz * CD * CN;   // [1024][2048] fp8

  f32x4 acc[4][4] = {};
  gemm_core_f8_n128(A, CN, Bt, CN, m0, n0, CN, smem_raw, acc);

  const int tid = threadIdx.x, lane = tid & 63, wid = tid >> 6;
  const int wr = wid >> 1, wc = wid & 1, lr = lane & 15, kg = lane >> 4;
  const float inv_nm1 = 1.0f / (float)(CN - 1);
#pragma unroll
  for (int mi = 0; mi < 4; ++mi)
#pragma unroll
    for (int j = 0; j < 4; ++j) {
      const int row = m0 + wr * 64 + mi * 16 + kg * 4 + j;
      const float rl = 4.0f / lsum[(size_t)bz * CN + row];
#pragma unroll
      for (int ni = 0; ni < 4; ++ni) {
        const int col = n0 + wc * 64 + ni * 16 + lr;
        const float ctx = (vsum[bz * CD + col] - acc[mi][ni][j] * rl) * inv_nm1;
        out[(size_t)(bz * CN + row) * CD + col] = ctx;
      }
    }
}

// in-place LayerNorm + ReLU per row of 1024
__global__ __launch_bounds__(256) void ln_relu_kernel(float* __restrict__ io,
                                                      const float* __restrict__ gamma,
                                                      const float* __restrict__ beta)
{
  float* x = io + (size_t)blockIdx.x * CD;
  const int t = threadIdx.x;
  float4 v = ((const float4*)x)[t];
  float s = v.x + v.y + v.z + v.w;
  float q = v.x * v.x + v.y * v.y + v.z * v.z + v.w * v.w;
#pragma unroll
  for (int off = 1; off < 64; off <<= 1) {
    s += __shfl_xor(s, off);
    q += __shfl_xor(q, off);
  }
  __shared__ float ss[4], qq[4];
  const int w = t >> 6, lane = t & 63;
  if (lane == 0) { ss[w] = s; qq[w] = q; }
  __syncthreads();
  s = ss[0] + ss[1] + ss[2] + ss[3];
  q = qq[0] + qq[1] + qq[2] + qq[3];
  const float mean = s * (1.0f / CD);
  const float var  = q * (1.0f / CD) - mean * mean;
  const float rstd = rsqrtf(var + 1e-5f);
  const float4 g  = ((const float4*)gamma)[t];
  const float4 bb = ((const float4*)beta)[t];
  v.x = fmaxf(0.f, (v.x - mean) * rstd * g.x + bb.x);
  v.y = fmaxf(0.f, (v.y - mean) * rstd * g.y + bb.y);
  v.z = fmaxf(0.f, (v.z - mean) * rstd * g.z + bb.z);
  v.w = fmaxf(0.f, (v.w - mean) * rstd * g.w + bb.w);
  ((float4*)x)[t] = v;
}

// ---------------------------------------------------------------------------
extern "C" void kernel_launch(void* const* d_in, const int* in_sizes, int n_in,
                              void* d_out, int out_size, void* d_ws, size_t ws_size,
                              hipStream_t stream)
{
  (void)in_sizes; (void)n_in; (void)out_size; (void)ws_size;
  const float* x1    = (const float*)d_in[0];
  const float* x2    = (const float*)d_in[1];
  const float* Wq    = (const float*)d_in[2];
  const float* bq    = (const float*)d_in[3];
  const float* Wk    = (const float*)d_in[4];
  const float* bk    = (const float*)d_in[5];
  const float* Wv    = (const float*)d_in[6];
  const float* bv    = (const float*)d_in[7];
  const float* gamma = (const float*)d_in[8];
  const float* beta  = (const float*)d_in[9];
  float* out = (float*)d_out;

  const int LDS_BIG = 131072, LDS_MID = 98304;
  hipFuncSetAttribute((const void*)kv_kernel,
                      hipFuncAttributeMaxDynamicSharedMemorySize, LDS_BIG);
  hipFuncSetAttribute((const void*)scores_kernel,
                      hipFuncAttributeMaxDynamicSharedMemorySize, LDS_BIG);
  hipFuncSetAttribute((const void*)q_kernel,
                      hipFuncAttributeMaxDynamicSharedMemorySize, LDS_MID);
  hipFuncSetAttribute((const void*)pv_kernel,
                      hipFuncAttributeMaxDynamicSharedMemorySize, LDS_MID);

  char* p = (char*)d_ws;
  auto alloc = [&](size_t bytes) -> char* {
    char* r = p;
    p += (bytes + 255) & ~(size_t)255;
    return r;
  };
  u16* x1b   = (u16*)alloc((size_t)CM * CD * 2);
  u16* x2b   = (u16*)alloc((size_t)CM * CD * 2);
  u16* WqT   = (u16*)alloc((size_t)CD * CD * 2);
  u16* WkvT  = (u16*)alloc((size_t)2 * CD * CD * 2);
  u8*  Qf8   = (u8*)alloc((size_t)CM * CD);
  u8*  Kf8   = (u8*)alloc((size_t)CM * CD);
  u8*  Vt8   = (u8*)alloc((size_t)CM * CD);
  u8*  Pf8   = (u8*)alloc((size_t)CB * CN * CN);
  float* ls  = (float*)alloc((size_t)CB * CN * 4);
  float* vs  = (float*)alloc((size_t)CB * CD * 4);

  hipMemsetAsync(ls, 0, (size_t)CB * CN * 4, stream);
  hipMemsetAsync(vs, 0, (size_t)CB * CD * 4, stream);

  // f32 -> bf16 inputs (one launch)
  {
    dim3 g(CM * CD / 1024, 2);
    cvt_bf16_kernel<<<g, 256, 0, stream>>>(x1, x1b, x2, x2b);
  }

  // W transposes (one launch)
  {
    dim3 g(32, 32, 3), blk(32, 8);
    transpose_w_kernel<<<g, blk, 0, stream>>>(Wq, Wk, Wv, WqT, WkvT);
  }

  // fused K|V projection: K fp8 + Vt fp8 + vsum (256 blocks)
  {
    dim3 g(32, 8);
    kv_kernel<<<g, 512, LDS_BIG, stream>>>(x2b, WkvT, bk, bv, Kf8, Vt8, vs);
  }

  // Q projection (256 blocks), fp8 out
  {
    dim3 g(32, 8);
    q_kernel<<<g, 512, LDS_MID, stream>>>(x1b, WqT, bq, Qf8);
  }

  // P/4 = exp(QK^T/32)/4 (fp8), l = rowsum
  {
    dim3 g(8, 8, CB);
    scores_kernel<<<g, 512, LDS_BIG, stream>>>(Qf8, Kf8, Pf8, ls);
  }

  // out = (vsum - 4*P@V/l) / (N-1)
  {
    dim3 g(8, 8, CB);
    pv_kernel<<<g, 512, LDS_MID, stream>>>(Pf8, Vt8, ls, vs, out);
  }

  // LayerNorm + ReLU in place
  ln_relu_kernel<<<CM, 256, 0, stream>>>(out, gamma, beta);
}

// Round 9
// 149.369 us; speedup vs baseline: 1.3450x; 1.0696x over previous
//
#include <hip/hip_runtime.h>

typedef __attribute__((ext_vector_type(8))) short bf16x8;
typedef __attribute__((ext_vector_type(4))) float f32x4;
typedef __attribute__((ext_vector_type(4))) int   i32x4;
typedef __attribute__((ext_vector_type(8))) int   i32x8;
typedef unsigned short u16;
typedef unsigned int u32;
typedef unsigned char u8;

#define DEV static __device__ __forceinline__

// problem sizes (fixed by the reference)
#define CB 4
#define CN 2048
#define CD 1024
#define CM 8192   // CB*CN

DEV u16 f2bf(float f) {
  u32 u = __float_as_uint(f);
  u = (u + 0x7FFFu + ((u >> 16) & 1u)) >> 16;
  return (u16)u;
}
DEV float bf2f(u16 h) { return __uint_as_float(((u32)h) << 16); }

DEV u8 f2fp8(float f) {
  return (u8)(__builtin_amdgcn_cvt_pk_fp8_f32(f, 0.f, 0, false) & 0xff);
}
DEV u32 pk_fp8x4(float a, float b, float c, float d) {
  const int p01 = __builtin_amdgcn_cvt_pk_fp8_f32(a, b, 0, false);
  const int p23 = __builtin_amdgcn_cvt_pk_fp8_f32(c, d, 0, false);
  return (u32)(p01 & 0xffff) | ((u32)(p23 & 0xffff) << 16);
}

#define GLD16(gsrc, ldst)                                                        \
  __builtin_amdgcn_global_load_lds(                                              \
      (const __attribute__((address_space(1))) void*)(gsrc),                     \
      (__attribute__((address_space(3))) void*)(ldst), 16, 0, 0)

#define SBAR()  asm volatile("s_barrier" ::: "memory")
#define WAITL() asm volatile("s_waitcnt lgkmcnt(0)" ::: "memory")
#define WAITV0() asm volatile("s_waitcnt vmcnt(0)" ::: "memory")

// unit-scale (E8M0=127) fp8xfp8 K=128 MFMA
#define MFMA_F8(a, b, c)                                                         \
  __builtin_amdgcn_mfma_scale_f32_16x16x128_f8f6f4((a), (b), (c), 0, 0, 0, 127,  \
                                                   0, 127)

// ---------------------------------------------------------------------------
// fp8 LDS tiles: [rows][128 bytes], XOR swizzle byte ^= ((byte>>7)&7)<<4
// (proven 0-conflict 128B-row layout). Per-lane fragment = 32B (2x b128).
// ---------------------------------------------------------------------------
DEV i32x8 lds_read_f8(const char* region, int row, int kbyte) {
  int b0 = row * 128 + kbyte;      b0 ^= ((b0 >> 7) & 7) << 4;
  int b1 = row * 128 + kbyte + 16; b1 ^= ((b1 >> 7) & 7) << 4;
  i32x4 lo = *(const i32x4*)(region + b0);
  i32x4 hi = *(const i32x4*)(region + b1);
  i32x8 r;
  r[0] = lo[0]; r[1] = lo[1]; r[2] = lo[2]; r[3] = lo[3];
  r[4] = hi[0]; r[5] = hi[1]; r[6] = hi[2]; r[7] = hi[3];
  return r;
}

// stage fp8 [256 rows][128B] tile (32KB): 2048 chunks, 4/thread
DEV void stage_f8_256(const u8* __restrict__ g, int ld, int row0, int kb,
                      char* dst, int tid) {
#pragma unroll
  for (int s = 0; s < 4; ++s) {
    const int c = tid + s * 512;
    const int row = c >> 3, sl = c & 7;
    const int lo = sl ^ (row & 7);
    GLD16(g + (size_t)(row0 + row) * ld + kb + lo * 16, dst + c * 16);
  }
}
// stage fp8 [128 rows][128B] tile (16KB): 1024 chunks, 2/thread
DEV void stage_f8_128(const u8* __restrict__ g, int ld, int row0, int kb,
                      char* dst, int tid) {
#pragma unroll
  for (int s = 0; s < 2; ++s) {
    const int c = tid + s * 512;
    const int row = c >> 3, sl = c & 7;
    const int lo = sl ^ (row & 7);
    GLD16(g + (size_t)(row0 + row) * ld + kb + lo * 16, dst + c * 16);
  }
}

// ---------------------------------------------------------------------------
// fp8 256x256 single-barrier core. 8 waves (2x4), acc[8][4], K-tile 128.
// LDS 128KB: per buffer A[256][128B]@0, B[256][128B]@32768.
// ---------------------------------------------------------------------------
DEV void gemm_core_f8(const u8* __restrict__ A, int lda,
                      const u8* __restrict__ Bt, int ldb,
                      int m0, int n0, int K, char* lds, f32x4 (&acc)[8][4])
{
  const int tid = threadIdx.x;
  const int lane = tid & 63;
  const int wid = tid >> 6;
  const int wr = wid >> 2, wc = wid & 3;
  const int lr = lane & 15, kg = lane >> 4;
  const int nt = K >> 7;

  char* buf0 = lds;
  char* buf1 = lds + 65536;

  stage_f8_256(A,  lda, m0, 0, buf0,         tid);
  stage_f8_256(Bt, ldb, n0, 0, buf0 + 32768, tid);
  WAITV0();
  SBAR();

  for (int t = 0; t < nt; ++t) {
    char* cur = (t & 1) ? buf1 : buf0;
    char* nxt = (t & 1) ? buf0 : buf1;
    const int kb1 = (t + 1) << 7;

    if (t + 1 < nt) {
      stage_f8_256(A,  lda, m0, kb1, nxt,         tid);
      stage_f8_256(Bt, ldb, n0, kb1, nxt + 32768, tid);
    }

    i32x8 Bf[4];
#pragma unroll
    for (int n = 0; n < 4; ++n)
      Bf[n] = lds_read_f8(cur + 32768, wc * 64 + n * 16 + lr, kg * 32);

#pragma unroll
    for (int half = 0; half < 2; ++half) {
      i32x8 Af[4];
#pragma unroll
      for (int m = 0; m < 4; ++m)
        Af[m] = lds_read_f8(cur, wr * 128 + half * 64 + m * 16 + lr, kg * 32);
      __builtin_amdgcn_s_setprio(1);
#pragma unroll
      for (int m = 0; m < 4; ++m)
#pragma unroll
        for (int n = 0; n < 4; ++n)
          acc[half * 4 + m][n] = MFMA_F8(Af[m], Bf[n], acc[half * 4 + m][n]);
      __builtin_amdgcn_s_setprio(0);
    }

    WAITV0();
    SBAR();
  }
}

// ---------------------------------------------------------------------------
// fp8 256x128 core. 8 waves (4x2), acc[4][4]. LDS 96KB: per buffer
// A[256][128B]@0, B[128][128B]@32768; buffer stride 49152.
// ---------------------------------------------------------------------------
DEV void gemm_core_f8_n128(const u8* __restrict__ A, int lda,
                           const u8* __restrict__ Bt, int ldb,
                           int m0, int n0, int K, char* lds, f32x4 (&acc)[4][4])
{
  const int tid = threadIdx.x;
  const int lane = tid & 63;
  const int wid = tid >> 6;
  const int wr = wid >> 1, wc = wid & 1;
  const int lr = lane & 15, kg = lane >> 4;
  const int nt = K >> 7;

  char* buf0 = lds;
  char* buf1 = lds + 49152;

  stage_f8_256(A,  lda, m0, 0, buf0,         tid);
  stage_f8_128(Bt, ldb, n0, 0, buf0 + 32768, tid);
  WAITV0();
  SBAR();

  for (int t = 0; t < nt; ++t) {
    char* cur = (t & 1) ? buf1 : buf0;
    char* nxt = (t & 1) ? buf0 : buf1;
    const int kb1 = (t + 1) << 7;

    if (t + 1 < nt) {
      stage_f8_256(A,  lda, m0, kb1, nxt,         tid);
      stage_f8_128(Bt, ldb, n0, kb1, nxt + 32768, tid);
    }

    i32x8 Af[4], Bf[4];
#pragma unroll
    for (int m = 0; m < 4; ++m)
      Af[m] = lds_read_f8(cur, wr * 64 + m * 16 + lr, kg * 32);
#pragma unroll
    for (int n = 0; n < 4; ++n)
      Bf[n] = lds_read_f8(cur + 32768, wc * 64 + n * 16 + lr, kg * 32);

    __builtin_amdgcn_s_setprio(1);
#pragma unroll
    for (int m = 0; m < 4; ++m)
#pragma unroll
      for (int n = 0; n < 4; ++n)
        acc[m][n] = MFMA_F8(Af[m], Bf[n], acc[m][n]);
    __builtin_amdgcn_s_setprio(0);

    WAITV0();
    SBAR();
  }
}

// ---------------------------------------------------------------------------
// f32 -> fp8 convert; z=1 (x2) also accumulates exact f32 colsum partials.
// Block: 32 rows x 1024 cols; thread: 4 cols x 32 rows.
// ---------------------------------------------------------------------------
__global__ __launch_bounds__(256) void cvt_kernel(
    const float* __restrict__ x1, u8* __restrict__ x1f8,
    const float* __restrict__ x2, u8* __restrict__ x2f8,
    float* __restrict__ csum)
{
  const int z = blockIdx.y;
  const float* in = z ? x2 : x1;
  u8* out = z ? x2f8 : x1f8;
  const int bx = blockIdx.x, tid = threadIdx.x;
  const int col = tid * 4;
  float4 s4 = {0.f, 0.f, 0.f, 0.f};
#pragma unroll 4
  for (int r = 0; r < 32; ++r) {
    const size_t row = (size_t)bx * 32 + r;
    const float4 v = *(const float4*)(in + row * CD + col);
    *(u32*)(out + row * CD + col) = pk_fp8x4(v.x, v.y, v.z, v.w);
    if (z) { s4.x += v.x; s4.y += v.y; s4.z += v.z; s4.w += v.w; }
  }
  if (z) {
    const int b = bx >> 6;   // 32 rows/block, 2048 rows/batch
    float* cb = csum + b * CD + col;
    atomicAdd(cb + 0, s4.x);
    atomicAdd(cb + 1, s4.y);
    atomicAdd(cb + 2, s4.z);
    atomicAdd(cb + 3, s4.w);
  }
}

// W [1024][1024] f32 -> WT [n][k] fp8; z selects Wq/Wk/Wv
__global__ __launch_bounds__(256) void transpose_w_kernel(
    const float* __restrict__ Wq, const float* __restrict__ Wk,
    const float* __restrict__ Wv, u8* __restrict__ WqT8,
    u8* __restrict__ WkT8, u8* __restrict__ WvT8)
{
  __shared__ float tile[32][33];
  const int z = blockIdx.z;
  const float* W = (z == 0) ? Wq : ((z == 1) ? Wk : Wv);
  u8* WT = (z == 0) ? WqT8 : ((z == 1) ? WkT8 : WvT8);
  const int tx = threadIdx.x, ty = threadIdx.y;   // 32 x 8
  const int bx = blockIdx.x, by = blockIdx.y;
#pragma unroll
  for (int i = 0; i < 4; ++i)
    tile[ty + i * 8][tx] = W[(size_t)(by * 32 + ty + i * 8) * CD + bx * 32 + tx];
  __syncthreads();
#pragma unroll
  for (int i = 0; i < 4; ++i)
    WT[(size_t)(bx * 32 + ty + i * 8) * CD + by * 32 + tx] =
        f2fp8(tile[tx][ty + i * 8]);
}

// ---------------------------------------------------------------------------
// EXACT vsum: vsum[b][d] = sum_k csum[b][k]*Wv[k][d] + 2048*bv[d]  (all f32)
// grid (8 dchunks, 4 b), 256 threads: 2 k-halves x 128 d.
// ---------------------------------------------------------------------------
__global__ __launch_bounds__(256) void vsum_mv_kernel(
    const float* __restrict__ csum, const float* __restrict__ Wv,
    const float* __restrict__ bv, float* __restrict__ vsum)
{
  __shared__ float sh[256];
  const int dc = blockIdx.x, b = blockIdx.y;
  const int tid = threadIdx.x;
  const int dl = tid & 127, kh = tid >> 7;
  const int d = dc * 128 + dl;
  const float* cb = csum + b * CD;
  float p0 = 0.f, p1 = 0.f, p2 = 0.f, p3 = 0.f;
  const int k0 = kh * 512;
  for (int k = k0; k < k0 + 512; k += 4) {
    p0 += cb[k + 0] * Wv[(size_t)(k + 0) * CD + d];
    p1 += cb[k + 1] * Wv[(size_t)(k + 1) * CD + d];
    p2 += cb[k + 2] * Wv[(size_t)(k + 2) * CD + d];
    p3 += cb[k + 3] * Wv[(size_t)(k + 3) * CD + d];
  }
  sh[tid] = (p0 + p1) + (p2 + p3);
  __syncthreads();
  if (tid < 128)
    vsum[b * CD + dc * 128 + tid] =
        sh[tid] + sh[tid + 128] + 2048.0f * bv[dc * 128 + tid];
}

// ---------------------------------------------------------------------------
// fused Q|K projections (fp8 core): grid 256. by<4 -> Q, else K.
// ---------------------------------------------------------------------------
__global__ __launch_bounds__(512, 2) void qk_kernel(
    const u8* __restrict__ x1f8, const u8* __restrict__ x2f8,
    const u8* __restrict__ WqT8, const u8* __restrict__ WkT8,
    const float* __restrict__ bq, const float* __restrict__ bk,
    u8* __restrict__ Qf8, u8* __restrict__ Kf8)
{
  extern __shared__ char smem_raw[];
  const int flat = blockIdx.y * 32 + blockIdx.x;      // nwg=256
  const int s = (flat & 7) * 32 + (flat >> 3);        // XCD swizzle
  const int bx = s & 31, by = s >> 5;
  const int sel = by >> 2;
  const int m0 = bx * 256, n0 = (by & 3) * 256;
  const u8* A  = sel ? x2f8 : x1f8;
  const u8* Bt = sel ? WkT8 : WqT8;
  const float* bias = sel ? bk : bq;
  u8* Y = sel ? Kf8 : Qf8;

  f32x4 acc[8][4] = {};
  gemm_core_f8(A, CD, Bt, CD, m0, n0, CD, smem_raw, acc);

  const int tid = threadIdx.x, lane = tid & 63, wid = tid >> 6;
  const int wr = wid >> 2, wc = wid & 3, lr = lane & 15, kg = lane >> 4;
#pragma unroll
  for (int mi = 0; mi < 8; ++mi)
#pragma unroll
    for (int ni = 0; ni < 4; ++ni) {
      const int col = n0 + wc * 64 + ni * 16 + lr;
      const float bcol = bias[col];
#pragma unroll
      for (int j = 0; j < 4; ++j) {
        const int row = m0 + wr * 128 + mi * 16 + kg * 4 + j;
        Y[(size_t)row * CD + col] = f2fp8(acc[mi][ni][j] + bcol);
      }
    }
}

// ---------------------------------------------------------------------------
// V projection (fp8 n128 core) -> Vt8[b][d][n] via LDS transpose. grid 256.
// (vsum handled exactly by vsum_mv_kernel; V fp8 errors only touch attn@V.)
// ---------------------------------------------------------------------------
__global__ __launch_bounds__(512, 2) void v_kernel(
    const u8* __restrict__ x2f8, const u8* __restrict__ WvT8,
    const float* __restrict__ bv, u8* __restrict__ Vt8)
{
  extern __shared__ char smem_raw[];
  const int flat = blockIdx.y * 32 + blockIdx.x;      // nwg=256
  const int s = (flat & 7) * 32 + (flat >> 3);
  const int bx = s & 31, by = s >> 5;                 // 32 m-tiles, 8 d-tiles
  const int m0 = bx * 256, n0 = by * 128;

  f32x4 acc[4][4] = {};
  gemm_core_f8_n128(x2f8, CD, WvT8, CD, m0, n0, CD, smem_raw, acc);

  const int tid = threadIdx.x, lane = tid & 63, wid = tid >> 6;
  const int wr = wid >> 1, wc = wid & 1, lr = lane & 15, kg = lane >> 4;
  const int b = m0 >> 11;              // batch
  const int nwb = m0 & (CN - 1);       // n-offset within batch
  u8* ldsT = (u8*)smem_raw;            // [128 d][264] u8 = 33.8KB

  // write transposed fp8 (bias included), 4 consecutive n packed per u32
#pragma unroll
  for (int ni = 0; ni < 4; ++ni) {
    const int cl = wc * 64 + ni * 16 + lr;           // d within tile, 0..127
    const float bcol = bv[n0 + cl];
#pragma unroll
    for (int mi = 0; mi < 4; ++mi) {
      const int rowb = wr * 64 + mi * 16 + kg * 4;   // n within tile, 4-aligned
      *(u32*)(ldsT + cl * 264 + rowb) =
          pk_fp8x4(acc[mi][ni][0] + bcol, acc[mi][ni][1] + bcol,
                   acc[mi][ni][2] + bcol, acc[mi][ni][3] + bcol);
    }
  }
  WAITL();
  SBAR();
  // coalesced copy-out: 128 d x 256 n fp8 = 2048 16B chunks, 4/thread
#pragma unroll
  for (int i = 0; i < 4; ++i) {
    const int c = tid + i * 512;
    const int dl = c >> 4;             // 0..127
    const int nk = c & 15;             // 16B chunk
    i32x4 vv = *(const i32x4*)(ldsT + dl * 264 + nk * 16);
    *(i32x4*)(Vt8 + ((size_t)b * CD + n0 + dl) * CN + nwb + nk * 16) = vv;
  }
}

// ---------------------------------------------------------------------------
// P/4 = exp(Q*K^T/32)/4 (fp8), row sums l (f32) via atomics. grid (8,8,4)
// ---------------------------------------------------------------------------
__global__ __launch_bounds__(512, 2) void scores_kernel(
    const u8* __restrict__ Q, const u8* __restrict__ Km,
    u8* __restrict__ P, float* __restrict__ lsum)
{
  extern __shared__ char smem_raw[];
  const int flat = (blockIdx.z * 8 + blockIdx.y) * 8 + blockIdx.x;  // nwg=256
  const int s = (flat & 7) * 32 + (flat >> 3);
  const int bx = s & 7, by = (s >> 3) & 7, bz = s >> 6;
  const int m0 = bx * 256, n0 = by * 256;
  const u8* A  = Q  + (size_t)bz * CN * CD;
  const u8* Bt = Km + (size_t)bz * CN * CD;

  f32x4 acc[8][4] = {};
  gemm_core_f8(A, CD, Bt, CD, m0, n0, CD, smem_raw, acc);

  const int tid = threadIdx.x, lane = tid & 63, wid = tid >> 6;
  const int wr = wid >> 2, wc = wid & 3, lr = lane & 15, kg = lane >> 4;
  u8* Pb = P + (size_t)bz * CN * CN;
  float* lb = lsum + (size_t)bz * CN;
  const float sc = 0.03125f * 1.4426950408889634f;
#pragma unroll
  for (int mi = 0; mi < 8; ++mi) {
    float rs[4] = {0.f, 0.f, 0.f, 0.f};
#pragma unroll
    for (int ni = 0; ni < 4; ++ni) {
      const int col = n0 + wc * 64 + ni * 16 + lr;
#pragma unroll
      for (int j = 0; j < 4; ++j) {
        const int row = m0 + wr * 128 + mi * 16 + kg * 4 + j;
        const float pv = exp2f(acc[mi][ni][j] * sc);
        rs[j] += pv;
        Pb[(size_t)row * CN + col] = f2fp8(pv * 0.25f);
      }
    }
#pragma unroll
    for (int j = 0; j < 4; ++j) {
      float v = rs[j];
      v += __shfl_xor(v, 1);
      v += __shfl_xor(v, 2);
      v += __shfl_xor(v, 4);
      v += __shfl_xor(v, 8);
      if (lr == 0)
        atomicAdd(&lb[m0 + wr * 128 + mi * 16 + kg * 4 + j], v);
    }
  }
}

// ---------------------------------------------------------------------------
// ctx = (vsum - 4*(P/4 @ V)/l) / (N-1)  -> bf16. grid (8,8,4)=256.
// ---------------------------------------------------------------------------
__global__ __launch_bounds__(512, 2) void pv_kernel(
    const u8* __restrict__ P, const u8* __restrict__ Vt,
    const float* __restrict__ lsum, const float* __restrict__ vsum,
    u16* __restrict__ ctx)
{
  extern __shared__ char smem_raw[];
  const int flat = (blockIdx.z * 8 + blockIdx.y) * 8 + blockIdx.x;  // nwg=256
  const int s = (flat & 7) * 32 + (flat >> 3);
  const int bx = s & 7, by = (s >> 3) & 7, bz = s >> 6;
  const int m0 = bx * 256, n0 = by * 128;
  const u8* A  = P  + (size_t)bz * CN * CN;   // [2048][2048] fp8
  const u8* Bt = Vt + (size_t)bz * CD * CN;   // [1024][2048] fp8

  f32x4 acc[4][4] = {};
  gemm_core_f8_n128(A, CN, Bt, CN, m0, n0, CN, smem_raw, acc);

  const int tid = threadIdx.x, lane = tid & 63, wid = tid >> 6;
  const int wr = wid >> 1, wc = wid & 1, lr = lane & 15, kg = lane >> 4;
  const float inv_nm1 = 1.0f / (float)(CN - 1);
#pragma unroll
  for (int mi = 0; mi < 4; ++mi)
#pragma unroll
    for (int j = 0; j < 4; ++j) {
      const int row = m0 + wr * 64 + mi * 16 + kg * 4 + j;
      const float rl = 4.0f / lsum[(size_t)bz * CN + row];
#pragma unroll
      for (int ni = 0; ni < 4; ++ni) {
        const int col = n0 + wc * 64 + ni * 16 + lr;
        const float cv = (vsum[bz * CD + col] - acc[mi][ni][j] * rl) * inv_nm1;
        ctx[(size_t)(bz * CN + row) * CD + col] = f2bf(cv);
      }
    }
}

// LayerNorm + ReLU per row of 1024: bf16 ctx in, f32 out
__global__ __launch_bounds__(256) void ln_relu_kernel(
    const u16* __restrict__ ctx, const float* __restrict__ gamma,
    const float* __restrict__ beta, float* __restrict__ out)
{
  const u16* x = ctx + (size_t)blockIdx.x * CD;
  const int t = threadIdx.x;
  const ushort4 uv = ((const ushort4*)x)[t];
  float v0 = bf2f(uv.x), v1 = bf2f(uv.y), v2 = bf2f(uv.z), v3 = bf2f(uv.w);
  float s = v0 + v1 + v2 + v3;
  float q = v0 * v0 + v1 * v1 + v2 * v2 + v3 * v3;
#pragma unroll
  for (int off = 1; off < 64; off <<= 1) {
    s += __shfl_xor(s, off);
    q += __shfl_xor(q, off);
  }
  __shared__ float ss[4], qq[4];
  const int w = t >> 6, lane = t & 63;
  if (lane == 0) { ss[w] = s; qq[w] = q; }
  __syncthreads();
  s = ss[0] + ss[1] + ss[2] + ss[3];
  q = qq[0] + qq[1] + qq[2] + qq[3];
  const float mean = s * (1.0f / CD);
  const float var  = q * (1.0f / CD) - mean * mean;
  const float rstd = rsqrtf(var + 1e-5f);
  const float4 g  = ((const float4*)gamma)[t];
  const float4 bb = ((const float4*)beta)[t];
  float4 o;
  o.x = fmaxf(0.f, (v0 - mean) * rstd * g.x + bb.x);
  o.y = fmaxf(0.f, (v1 - mean) * rstd * g.y + bb.y);
  o.z = fmaxf(0.f, (v2 - mean) * rstd * g.z + bb.z);
  o.w = fmaxf(0.f, (v3 - mean) * rstd * g.w + bb.w);
  ((float4*)(out + (size_t)blockIdx.x * CD))[t] = o;
}

// ---------------------------------------------------------------------------
extern "C" void kernel_launch(void* const* d_in, const int* in_sizes, int n_in,
                              void* d_out, int out_size, void* d_ws, size_t ws_size,
                              hipStream_t stream)
{
  (void)in_sizes; (void)n_in; (void)out_size; (void)ws_size;
  const float* x1    = (const float*)d_in[0];
  const float* x2    = (const float*)d_in[1];
  const float* Wq    = (const float*)d_in[2];
  const float* bq    = (const float*)d_in[3];
  const float* Wk    = (const float*)d_in[4];
  const float* bk    = (const float*)d_in[5];
  const float* Wv    = (const float*)d_in[6];
  const float* bv    = (const float*)d_in[7];
  const float* gamma = (const float*)d_in[8];
  const float* beta  = (const float*)d_in[9];
  float* out = (float*)d_out;

  const int LDS_BIG = 131072, LDS_MID = 98304;
  hipFuncSetAttribute((const void*)qk_kernel,
                      hipFuncAttributeMaxDynamicSharedMemorySize, LDS_BIG);
  hipFuncSetAttribute((const void*)scores_kernel,
                      hipFuncAttributeMaxDynamicSharedMemorySize, LDS_BIG);
  hipFuncSetAttribute((const void*)v_kernel,
                      hipFuncAttributeMaxDynamicSharedMemorySize, LDS_MID);
  hipFuncSetAttribute((const void*)pv_kernel,
                      hipFuncAttributeMaxDynamicSharedMemorySize, LDS_MID);

  char* p = (char*)d_ws;
  auto alloc = [&](size_t bytes) -> char* {
    char* r = p;
    p += (bytes + 255) & ~(size_t)255;
    return r;
  };
  u8*  x1f8  = (u8*)alloc((size_t)CM * CD);
  u8*  x2f8  = (u8*)alloc((size_t)CM * CD);
  u8*  WqT8  = (u8*)alloc((size_t)CD * CD);
  u8*  WkT8  = (u8*)alloc((size_t)CD * CD);
  u8*  WvT8  = (u8*)alloc((size_t)CD * CD);
  u8*  Qf8   = (u8*)alloc((size_t)CM * CD);
  u8*  Kf8   = (u8*)alloc((size_t)CM * CD);
  u8*  Vt8   = (u8*)alloc((size_t)CM * CD);
  u8*  Pf8   = (u8*)alloc((size_t)CB * CN * CN);
  u16* ctxb  = (u16*)alloc((size_t)CM * CD * 2);
  float* ls  = (float*)alloc((size_t)CB * CN * 4);
  float* vs  = (float*)alloc((size_t)CB * CD * 4);
  float* cs  = (float*)alloc((size_t)CB * CD * 4);

  hipMemsetAsync(ls, 0, (size_t)CB * CN * 4, stream);
  hipMemsetAsync(cs, 0, (size_t)CB * CD * 4, stream);

  // f32 -> fp8 inputs + exact colsum(x2) partials
  {
    dim3 g(256, 2);
    cvt_kernel<<<g, 256, 0, stream>>>(x1, x1f8, x2, x2f8, cs);
  }

  // W transposes -> fp8 (one launch)
  {
    dim3 g(32, 32, 3), blk(32, 8);
    transpose_w_kernel<<<g, blk, 0, stream>>>(Wq, Wk, Wv, WqT8, WkT8, WvT8);
  }

  // exact vsum = colsum(x2).Wv + 2048*bv  (f32)
  {
    dim3 g(8, CB);
    vsum_mv_kernel<<<g, 256, 0, stream>>>(cs, Wv, bv, vs);
  }

  // fused Q|K projections (fp8, 256 blocks)
  {
    dim3 g(32, 8);
    qk_kernel<<<g, 512, LDS_BIG, stream>>>(x1f8, x2f8, WqT8, WkT8, bq, bk,
                                           Qf8, Kf8);
  }

  // V projection -> Vt8 (fp8, 256 blocks)
  {
    dim3 g(32, 8);
    v_kernel<<<g, 512, LDS_MID, stream>>>(x2f8, WvT8, bv, Vt8);
  }

  // P/4 = exp(QK^T/32)/4 (fp8), l = rowsum
  {
    dim3 g(8, 8, CB);
    scores_kernel<<<g, 512, LDS_BIG, stream>>>(Qf8, Kf8, Pf8, ls);
  }

  // ctx = (vsum - 4*P@V/l)/(N-1) -> bf16
  {
    dim3 g(8, 8, CB);
    pv_kernel<<<g, 512, LDS_MID, stream>>>(Pf8, Vt8, ls, vs, ctxb);
  }

  // LayerNorm + ReLU (bf16 in, f32 out)
  ln_relu_kernel<<<CM, 256, 0, stream>>>(ctxb, gamma, beta, out);
}

// Round 10
// 143.510 us; speedup vs baseline: 1.3999x; 1.0408x over previous
//
#include <hip/hip_runtime.h>

typedef __attribute__((ext_vector_type(4))) float f32x4;
typedef __attribute__((ext_vector_type(4))) int   i32x4;
typedef __attribute__((ext_vector_type(8))) int   i32x8;
typedef unsigned short u16;
typedef unsigned int u32;
typedef unsigned char u8;

#define DEV static __device__ __forceinline__

// problem sizes (fixed by the reference)
#define CB 4
#define CN 2048
#define CD 1024
#define CM 8192   // CB*CN

DEV u16 f2bf(float f) {
  u32 u = __float_as_uint(f);
  u = (u + 0x7FFFu + ((u >> 16) & 1u)) >> 16;
  return (u16)u;
}
DEV float bf2f(u16 h) { return __uint_as_float(((u32)h) << 16); }

DEV u8 f2fp8(float f) {
  return (u8)(__builtin_amdgcn_cvt_pk_fp8_f32(f, 0.f, 0, false) & 0xff);
}
DEV u32 pk_fp8x4(float a, float b, float c, float d) {
  const int p01 = __builtin_amdgcn_cvt_pk_fp8_f32(a, b, 0, false);
  const int p23 = __builtin_amdgcn_cvt_pk_fp8_f32(c, d, 0, false);
  return (u32)(p01 & 0xffff) | ((u32)(p23 & 0xffff) << 16);
}

#define GLD16(gsrc, ldst)                                                        \
  __builtin_amdgcn_global_load_lds(                                              \
      (const __attribute__((address_space(1))) void*)(gsrc),                     \
      (__attribute__((address_space(3))) void*)(ldst), 16, 0, 0)

#define SBAR()  asm volatile("s_barrier" ::: "memory")
#define WAITL() asm volatile("s_waitcnt lgkmcnt(0)" ::: "memory")
#define WAITV6() asm volatile("s_waitcnt vmcnt(6)" ::: "memory")
#define WAITV4() asm volatile("s_waitcnt vmcnt(4)" ::: "memory")
#define WAITV2() asm volatile("s_waitcnt vmcnt(2)" ::: "memory")
#define WAITV0() asm volatile("s_waitcnt vmcnt(0)" ::: "memory")

// unit-scale (E8M0=127) fp8xfp8 K=128 MFMA
#define MFMA_F8(a, b, c)                                                         \
  __builtin_amdgcn_mfma_scale_f32_16x16x128_f8f6f4((a), (b), (c), 0, 0, 0, 127,  \
                                                   0, 127)

// ---------------------------------------------------------------------------
// fp8 LDS tiles: [rows][128 bytes], XOR swizzle byte ^= ((byte>>7)&7)<<4
// (proven 0-conflict 128B-row layout). Per-lane fragment = 32B (2x b128).
// ---------------------------------------------------------------------------
DEV i32x8 lds_read_f8(const char* region, int row, int kbyte) {
  int b0 = row * 128 + kbyte;      b0 ^= ((b0 >> 7) & 7) << 4;
  int b1 = row * 128 + kbyte + 16; b1 ^= ((b1 >> 7) & 7) << 4;
  i32x4 lo = *(const i32x4*)(region + b0);
  i32x4 hi = *(const i32x4*)(region + b1);
  i32x8 r;
  r[0] = lo[0]; r[1] = lo[1]; r[2] = lo[2]; r[3] = lo[3];
  r[4] = hi[0]; r[5] = hi[1]; r[6] = hi[2]; r[7] = hi[3];
  return r;
}

// stage fp8 [256 rows][128B] (32KB): 2048 chunks, 4/thread (pre-swizzled src)
DEV void stage_f8_256(const u8* __restrict__ g, int ld, int row0, int kb,
                      char* dst, int tid) {
#pragma unroll
  for (int s = 0; s < 4; ++s) {
    const int c = tid + s * 512;
    const int row = c >> 3, sl = c & 7;
    const int lo = sl ^ (row & 7);
    GLD16(g + (size_t)(row0 + row) * ld + kb + lo * 16, dst + c * 16);
  }
}
// stage fp8 [128 rows][128B] (16KB): 1024 chunks, 2/thread
DEV void stage_f8_128(const u8* __restrict__ g, int ld, int row0, int kb,
                      char* dst, int tid) {
#pragma unroll
  for (int s = 0; s < 2; ++s) {
    const int c = tid + s * 512;
    const int row = c >> 3, sl = c & 7;
    const int lo = sl ^ (row & 7);
    GLD16(g + (size_t)(row0 + row) * ld + kb + lo * 16, dst + c * 16);
  }
}
// stage A-quarter-pair for 256^2 core: local rows {off..off+63, 128+off..+63}
// (1024 chunks, 2/thread)
DEV void stage_f8_qpair(const u8* __restrict__ g, int ld, int m0, int kb,
                        char* region, int off, int tid) {
#pragma unroll
  for (int i = 0; i < 2; ++i) {
    const int c = tid + i * 512;
    const int q = c >> 9;              // 0,1
    const int r = (c >> 3) & 63;
    const int sl = c & 7;
    const int lrow = q * 128 + off + r;
    const int lo = sl ^ (lrow & 7);
    GLD16(g + (size_t)(m0 + lrow) * ld + kb + lo * 16,
          region + lrow * 128 + sl * 16);
  }
}
// stage A-stripe set for n128 core: local rows s*64+off..+31, s=0..3
// (1024 chunks, 2/thread)
DEV void stage_f8_spair(const u8* __restrict__ g, int ld, int m0, int kb,
                        char* region, int off, int tid) {
#pragma unroll
  for (int i = 0; i < 2; ++i) {
    const int c = tid + i * 512;
    const int s = c >> 8;              // 0..3
    const int r = (c >> 3) & 31;
    const int sl = c & 7;
    const int lrow = s * 64 + off + r;
    const int lo = sl ^ (lrow & 7);
    GLD16(g + (size_t)(m0 + lrow) * ld + kb + lo * 16,
          region + lrow * 128 + sl * 16);
  }
}

// ---------------------------------------------------------------------------
// fp8 256x256 2-seg counted-wait core. 8 waves (2x4), acc[8][4], K-tile 128.
// LDS 128KB: per buffer A[256][128B]@0, B[256][128B]@32768.
// Row-phase split: every wave reads A-half0 rows (q0:0-63 / q2:128-191) in
// seg1 and A-half1 rows (q1/q3) in seg2; B fully read in seg1 (regs kept).
// Stage plan: seg1 issues X(t+1)={B,Aq02} (6/thread); seg2 issues
// Y(t+1)={Aq13} (2/thread). Waits: mid vmcnt(6) drains Y(t) (issued a full
// segment earlier; every wave drains its own loads pre-barrier -> cross-wave
// safe); end vmcnt(2) drains X(t+1), keeps Y(t+1) in flight. No vmcnt(0) in
// the steady loop. Tails fall back to vmcnt(0).
// ---------------------------------------------------------------------------
DEV void gemm_core_f8(const u8* __restrict__ A, int lda,
                      const u8* __restrict__ Bt, int ldb,
                      int m0, int n0, int K, char* lds, f32x4 (&acc)[8][4])
{
  const int tid = threadIdx.x;
  const int lane = tid & 63;
  const int wid = tid >> 6;
  const int wr = wid >> 2, wc = wid & 3;
  const int lr = lane & 15, kg = lane >> 4;
  const int nt = K >> 7;

  char* buf0 = lds;
  char* buf1 = lds + 65536;

  // prologue: X(0) then Y(0); drain X, keep Y in flight
  stage_f8_256(Bt, ldb, n0, 0, buf0 + 32768, tid);   // 4
  stage_f8_qpair(A, lda, m0, 0, buf0, 0, tid);       // 2 (q0,q2)
  stage_f8_qpair(A, lda, m0, 0, buf0, 64, tid);      // 2 (q1,q3) = Y(0)
  WAITV2();
  SBAR();

  for (int t = 0; t < nt; ++t) {
    char* cur = (t & 1) ? buf1 : buf0;
    char* nxt = (t & 1) ? buf0 : buf1;
    const int kb1 = (t + 1) << 7;

    // ---- seg1: issue X(t+1); read Bf(all) + Af half0; MFMA half0
    if (t + 1 < nt) {
      stage_f8_256(Bt, ldb, n0, kb1, nxt + 32768, tid);
      stage_f8_qpair(A, lda, m0, kb1, nxt, 0, tid);
    }
    i32x8 Bf[4], Af[4];
#pragma unroll
    for (int n = 0; n < 4; ++n)
      Bf[n] = lds_read_f8(cur + 32768, wc * 64 + n * 16 + lr, kg * 32);
#pragma unroll
    for (int m = 0; m < 4; ++m)
      Af[m] = lds_read_f8(cur, wr * 128 + m * 16 + lr, kg * 32);
    __builtin_amdgcn_s_setprio(1);
#pragma unroll
    for (int m = 0; m < 4; ++m)
#pragma unroll
      for (int n = 0; n < 4; ++n)
        acc[m][n] = MFMA_F8(Af[m], Bf[n], acc[m][n]);
    __builtin_amdgcn_s_setprio(0);
    if (t + 1 < nt) { WAITV6(); } else { WAITV0(); }
    SBAR();

    // ---- seg2: issue Y(t+1); read Af half1; MFMA half1
    if (t + 1 < nt) stage_f8_qpair(A, lda, m0, kb1, nxt, 64, tid);
#pragma unroll
    for (int m = 0; m < 4; ++m)
      Af[m] = lds_read_f8(cur, wr * 128 + 64 + m * 16 + lr, kg * 32);
    __builtin_amdgcn_s_setprio(1);
#pragma unroll
    for (int m = 0; m < 4; ++m)
#pragma unroll
      for (int n = 0; n < 4; ++n)
        acc[4 + m][n] = MFMA_F8(Af[m], Bf[n], acc[4 + m][n]);
    __builtin_amdgcn_s_setprio(0);
    if (t + 1 < nt) { WAITV2(); } else { WAITV0(); }
    SBAR();
  }
}

// ---------------------------------------------------------------------------
// fp8 256x128 2-seg core. 8 waves (4x2), acc[4][4]. LDS 96KB: per buffer
// A[256][128B]@0, B[128][128B]@32768; buffer stride 49152.
// X={B, A even 32-row stripes} (4/thread), Y={A odd stripes} (2/thread).
// Waits: mid vmcnt(4), end vmcnt(2); tails vmcnt(0).
// ---------------------------------------------------------------------------
DEV void gemm_core_f8_n128(const u8* __restrict__ A, int lda,
                           const u8* __restrict__ Bt, int ldb,
                           int m0, int n0, int K, char* lds, f32x4 (&acc)[4][4])
{
  const int tid = threadIdx.x;
  const int lane = tid & 63;
  const int wid = tid >> 6;
  const int wr = wid >> 1, wc = wid & 1;
  const int lr = lane & 15, kg = lane >> 4;
  const int nt = K >> 7;

  char* buf0 = lds;
  char* buf1 = lds + 49152;

  stage_f8_128(Bt, ldb, n0, 0, buf0 + 32768, tid);   // 2
  stage_f8_spair(A, lda, m0, 0, buf0, 0, tid);       // 2 (even stripes)
  stage_f8_spair(A, lda, m0, 0, buf0, 32, tid);      // 2 (odd) = Y(0)
  WAITV2();
  SBAR();

  for (int t = 0; t < nt; ++t) {
    char* cur = (t & 1) ? buf1 : buf0;
    char* nxt = (t & 1) ? buf0 : buf1;
    const int kb1 = (t + 1) << 7;

    // ---- seg1: issue X(t+1); read Bf(all) + Af mi 0,1; MFMA
    if (t + 1 < nt) {
      stage_f8_128(Bt, ldb, n0, kb1, nxt + 32768, tid);
      stage_f8_spair(A, lda, m0, kb1, nxt, 0, tid);
    }
    i32x8 Bf[4], Af[2];
#pragma unroll
    for (int n = 0; n < 4; ++n)
      Bf[n] = lds_read_f8(cur + 32768, wc * 64 + n * 16 + lr, kg * 32);
#pragma unroll
    for (int m = 0; m < 2; ++m)
      Af[m] = lds_read_f8(cur, wr * 64 + m * 16 + lr, kg * 32);
    __builtin_amdgcn_s_setprio(1);
#pragma unroll
    for (int m = 0; m < 2; ++m)
#pragma unroll
      for (int n = 0; n < 4; ++n)
        acc[m][n] = MFMA_F8(Af[m], Bf[n], acc[m][n]);
    __builtin_amdgcn_s_setprio(0);
    if (t + 1 < nt) { WAITV4(); } else { WAITV0(); }
    SBAR();

    // ---- seg2: issue Y(t+1); read Af mi 2,3; MFMA
    if (t + 1 < nt) stage_f8_spair(A, lda, m0, kb1, nxt, 32, tid);
#pragma unroll
    for (int m = 0; m < 2; ++m)
      Af[m] = lds_read_f8(cur, wr * 64 + 32 + m * 16 + lr, kg * 32);
    __builtin_amdgcn_s_setprio(1);
#pragma unroll
    for (int m = 0; m < 2; ++m)
#pragma unroll
      for (int n = 0; n < 4; ++n)
        acc[2 + m][n] = MFMA_F8(Af[m], Bf[n], acc[2 + m][n]);
    __builtin_amdgcn_s_setprio(0);
    if (t + 1 < nt) { WAITV2(); } else { WAITV0(); }
    SBAR();
  }
}

// ---------------------------------------------------------------------------
// f32 -> fp8 convert; z=1 (x2) also accumulates exact f32 colsum partials.
// z=0 blocks 0..31 additionally zero lsum (replaces hipMemsetAsync).
// ---------------------------------------------------------------------------
__global__ __launch_bounds__(256) void cvt_kernel(
    const float* __restrict__ x1, u8* __restrict__ x1f8,
    const float* __restrict__ x2, u8* __restrict__ x2f8,
    float* __restrict__ csum, float* __restrict__ lsum)
{
  const int z = blockIdx.y;
  const float* in = z ? x2 : x1;
  u8* out = z ? x2f8 : x1f8;
  const int bx = blockIdx.x, tid = threadIdx.x;
  if (!z && bx < 32) lsum[bx * 256 + tid] = 0.f;   // zero ls (8192 f32)
  const int col = tid * 4;
  float4 s4 = {0.f, 0.f, 0.f, 0.f};
#pragma unroll 4
  for (int r = 0; r < 32; ++r) {
    const size_t row = (size_t)bx * 32 + r;
    const float4 v = *(const float4*)(in + row * CD + col);
    *(u32*)(out + row * CD + col) = pk_fp8x4(v.x, v.y, v.z, v.w);
    if (z) { s4.x += v.x; s4.y += v.y; s4.z += v.z; s4.w += v.w; }
  }
  if (z) {
    const int b = bx >> 6;   // 32 rows/block, 2048 rows/batch
    float* cb = csum + b * CD + col;
    atomicAdd(cb + 0, s4.x);
    atomicAdd(cb + 1, s4.y);
    atomicAdd(cb + 2, s4.z);
    atomicAdd(cb + 3, s4.w);
  }
}

// W [1024][1024] f32 -> WT [n][k] fp8; z selects Wq/Wk/Wv.
// z=0, by=0 blocks also zero csum (runs BEFORE cvt in launch order).
__global__ __launch_bounds__(256) void transpose_w_kernel(
    const float* __restrict__ Wq, const float* __restrict__ Wk,
    const float* __restrict__ Wv, u8* __restrict__ WqT8,
    u8* __restrict__ WkT8, u8* __restrict__ WvT8, float* __restrict__ csum)
{
  __shared__ float tile[32][33];
  const int z = blockIdx.z;
  const float* W = (z == 0) ? Wq : ((z == 1) ? Wk : Wv);
  u8* WT = (z == 0) ? WqT8 : ((z == 1) ? WkT8 : WvT8);
  const int tx = threadIdx.x, ty = threadIdx.y;   // 32 x 8
  const int bx = blockIdx.x, by = blockIdx.y;
  const int ft = ty * 32 + tx;
  if (z == 0 && by == 0 && ft < 128) csum[bx * 128 + ft] = 0.f;  // 4096 f32
#pragma unroll
  for (int i = 0; i < 4; ++i)
    tile[ty + i * 8][tx] = W[(size_t)(by * 32 + ty + i * 8) * CD + bx * 32 + tx];
  __syncthreads();
#pragma unroll
  for (int i = 0; i < 4; ++i)
    WT[(size_t)(bx * 32 + ty + i * 8) * CD + by * 32 + tx] =
        f2fp8(tile[tx][ty + i * 8]);
}

// ---------------------------------------------------------------------------
// EXACT vsum: vsum[b][d] = sum_k csum[b][k]*Wv[k][d] + 2048*bv[d]  (all f32)
// ---------------------------------------------------------------------------
__global__ __launch_bounds__(256) void vsum_mv_kernel(
    const float* __restrict__ csum, const float* __restrict__ Wv,
    const float* __restrict__ bv, float* __restrict__ vsum)
{
  __shared__ float sh[256];
  const int dc = blockIdx.x, b = blockIdx.y;
  const int tid = threadIdx.x;
  const int dl = tid & 127, kh = tid >> 7;
  const int d = dc * 128 + dl;
  const float* cb = csum + b * CD;
  float p0 = 0.f, p1 = 0.f, p2 = 0.f, p3 = 0.f;
  const int k0 = kh * 512;
  for (int k = k0; k < k0 + 512; k += 4) {
    p0 += cb[k + 0] * Wv[(size_t)(k + 0) * CD + d];
    p1 += cb[k + 1] * Wv[(size_t)(k + 1) * CD + d];
    p2 += cb[k + 2] * Wv[(size_t)(k + 2) * CD + d];
    p3 += cb[k + 3] * Wv[(size_t)(k + 3) * CD + d];
  }
  sh[tid] = (p0 + p1) + (p2 + p3);
  __syncthreads();
  if (tid < 128)
    vsum[b * CD + dc * 128 + tid] =
        sh[tid] + sh[tid + 128] + 2048.0f * bv[dc * 128 + tid];
}

// ---------------------------------------------------------------------------
// fused Q|K projections (fp8 core): grid 256. by<4 -> Q, else K.
// ---------------------------------------------------------------------------
__global__ __launch_bounds__(512, 2) void qk_kernel(
    const u8* __restrict__ x1f8, const u8* __restrict__ x2f8,
    const u8* __restrict__ WqT8, const u8* __restrict__ WkT8,
    const float* __restrict__ bq, const float* __restrict__ bk,
    u8* __restrict__ Qf8, u8* __restrict__ Kf8)
{
  extern __shared__ char smem_raw[];
  const int flat = blockIdx.y * 32 + blockIdx.x;      // nwg=256
  const int s = (flat & 7) * 32 + (flat >> 3);        // XCD swizzle
  const int bx = s & 31, by = s >> 5;
  const int sel = by >> 2;
  const int m0 = bx * 256, n0 = (by & 3) * 256;
  const u8* A  = sel ? x2f8 : x1f8;
  const u8* Bt = sel ? WkT8 : WqT8;
  const float* bias = sel ? bk : bq;
  u8* Y = sel ? Kf8 : Qf8;

  f32x4 acc[8][4] = {};
  gemm_core_f8(A, CD, Bt, CD, m0, n0, CD, smem_raw, acc);

  const int tid = threadIdx.x, lane = tid & 63, wid = tid >> 6;
  const int wr = wid >> 2, wc = wid & 3, lr = lane & 15, kg = lane >> 4;
#pragma unroll
  for (int mi = 0; mi < 8; ++mi)
#pragma unroll
    for (int ni = 0; ni < 4; ++ni) {
      const int col = n0 + wc * 64 + ni * 16 + lr;
      const float bcol = bias[col];
#pragma unroll
      for (int j = 0; j < 4; ++j) {
        const int row = m0 + wr * 128 + (mi >> 2) * 64 + (mi & 3) * 16 + kg * 4 + j;
        Y[(size_t)row * CD + col] = f2fp8(acc[mi][ni][j] + bcol);
      }
    }
}

// ---------------------------------------------------------------------------
// V projection (fp8 n128 core) -> Vt8[b][d][n] via LDS transpose. grid 256.
// ---------------------------------------------------------------------------
__global__ __launch_bounds__(512, 2) void v_kernel(
    const u8* __restrict__ x2f8, const u8* __restrict__ WvT8,
    const float* __restrict__ bv, u8* __restrict__ Vt8)
{
  extern __shared__ char smem_raw[];
  const int flat = blockIdx.y * 32 + blockIdx.x;      // nwg=256
  const int s = (flat & 7) * 32 + (flat >> 3);
  const int bx = s & 31, by = s >> 5;                 // 32 m-tiles, 8 d-tiles
  const int m0 = bx * 256, n0 = by * 128;

  f32x4 acc[4][4] = {};
  gemm_core_f8_n128(x2f8, CD, WvT8, CD, m0, n0, CD, smem_raw, acc);

  const int tid = threadIdx.x, lane = tid & 63, wid = tid >> 6;
  const int wr = wid >> 1, wc = wid & 1, lr = lane & 15, kg = lane >> 4;
  const int b = m0 >> 11;              // batch
  const int nwb = m0 & (CN - 1);       // n-offset within batch
  u8* ldsT = (u8*)smem_raw;            // [128 d][264] u8 = 33.8KB

#pragma unroll
  for (int ni = 0; ni < 4; ++ni) {
    const int cl = wc * 64 + ni * 16 + lr;           // d within tile, 0..127
    const float bcol = bv[n0 + cl];
#pragma unroll
    for (int mi = 0; mi < 4; ++mi) {
      const int rowb = wr * 64 + ((mi >> 1) * 32) + (mi & 1) * 16 + kg * 4;
      *(u32*)(ldsT + cl * 264 + rowb) =
          pk_fp8x4(acc[mi][ni][0] + bcol, acc[mi][ni][1] + bcol,
                   acc[mi][ni][2] + bcol, acc[mi][ni][3] + bcol);
    }
  }
  WAITL();
  SBAR();
#pragma unroll
  for (int i = 0; i < 4; ++i) {
    const int c = tid + i * 512;
    const int dl = c >> 4;             // 0..127
    const int nk = c & 15;             // 16B chunk
    i32x4 vv = *(const i32x4*)(ldsT + dl * 264 + nk * 16);
    *(i32x4*)(Vt8 + ((size_t)b * CD + n0 + dl) * CN + nwb + nk * 16) = vv;
  }
}

// ---------------------------------------------------------------------------
// P/4 = exp(Q*K^T/32)/4 (fp8), row sums l (f32) via atomics. grid (8,8,4)
// ---------------------------------------------------------------------------
__global__ __launch_bounds__(512, 2) void scores_kernel(
    const u8* __restrict__ Q, const u8* __restrict__ Km,
    u8* __restrict__ P, float* __restrict__ lsum)
{
  extern __shared__ char smem_raw[];
  const int flat = (blockIdx.z * 8 + blockIdx.y) * 8 + blockIdx.x;  // nwg=256
  const int s = (flat & 7) * 32 + (flat >> 3);
  const int bx = s & 7, by = (s >> 3) & 7, bz = s >> 6;
  const int m0 = bx * 256, n0 = by * 256;
  const u8* A  = Q  + (size_t)bz * CN * CD;
  const u8* Bt = Km + (size_t)bz * CN * CD;

  f32x4 acc[8][4] = {};
  gemm_core_f8(A, CD, Bt, CD, m0, n0, CD, smem_raw, acc);

  const int tid = threadIdx.x, lane = tid & 63, wid = tid >> 6;
  const int wr = wid >> 2, wc = wid & 3, lr = lane & 15, kg = lane >> 4;
  u8* Pb = P + (size_t)bz * CN * CN;
  float* lb = lsum + (size_t)bz * CN;
  const float sc = 0.03125f * 1.4426950408889634f;
#pragma unroll
  for (int mi = 0; mi < 8; ++mi) {
    float rs[4] = {0.f, 0.f, 0.f, 0.f};
#pragma unroll
    for (int ni = 0; ni < 4; ++ni) {
      const int col = n0 + wc * 64 + ni * 16 + lr;
#pragma unroll
      for (int j = 0; j < 4; ++j) {
        const int row = m0 + wr * 128 + (mi >> 2) * 64 + (mi & 3) * 16 + kg * 4 + j;
        const float pv = exp2f(acc[mi][ni][j] * sc);
        rs[j] += pv;
        Pb[(size_t)row * CN + col] = f2fp8(pv * 0.25f);
      }
    }
#pragma unroll
    for (int j = 0; j < 4; ++j) {
      float v = rs[j];
      v += __shfl_xor(v, 1);
      v += __shfl_xor(v, 2);
      v += __shfl_xor(v, 4);
      v += __shfl_xor(v, 8);
      if (lr == 0)
        atomicAdd(&lb[m0 + wr * 128 + (mi >> 2) * 64 + (mi & 3) * 16 + kg * 4 + j], v);
    }
  }
}

// ---------------------------------------------------------------------------
// ctx = (vsum - 4*(P/4 @ V)/l) / (N-1)  -> bf16. grid (8,8,4)=256.
// ---------------------------------------------------------------------------
__global__ __launch_bounds__(512, 2) void pv_kernel(
    const u8* __restrict__ P, const u8* __restrict__ Vt,
    const float* __restrict__ lsum, const float* __restrict__ vsum,
    u16* __restrict__ ctx)
{
  extern __shared__ char smem_raw[];
  const int flat = (blockIdx.z * 8 + blockIdx.y) * 8 + blockIdx.x;  // nwg=256
  const int s = (flat & 7) * 32 + (flat >> 3);
  const int bx = s & 7, by = (s >> 3) & 7, bz = s >> 6;
  const int m0 = bx * 256, n0 = by * 128;
  const u8* A  = P  + (size_t)bz * CN * CN;   // [2048][2048] fp8
  const u8* Bt = Vt + (size_t)bz * CD * CN;   // [1024][2048] fp8

  f32x4 acc[4][4] = {};
  gemm_core_f8_n128(A, CN, Bt, CN, m0, n0, CN, smem_raw, acc);

  const int tid = threadIdx.x, lane = tid & 63, wid = tid >> 6;
  const int wr = wid >> 1, wc = wid & 1, lr = lane & 15, kg = lane >> 4;
  const float inv_nm1 = 1.0f / (float)(CN - 1);
#pragma unroll
  for (int mi = 0; mi < 4; ++mi)
#pragma unroll
    for (int j = 0; j < 4; ++j) {
      const int row = m0 + wr * 64 + ((mi >> 1) * 32) + (mi & 1) * 16 + kg * 4 + j;
      const float rl = 4.0f / lsum[(size_t)bz * CN + row];
#pragma unroll
      for (int ni = 0; ni < 4; ++ni) {
        const int col = n0 + wc * 64 + ni * 16 + lr;
        const float cv = (vsum[bz * CD + col] - acc[mi][ni][j] * rl) * inv_nm1;
        ctx[(size_t)(bz * CN + row) * CD + col] = f2bf(cv);
      }
    }
}

// LayerNorm + ReLU per row of 1024: bf16 ctx in, f32 out
__global__ __launch_bounds__(256) void ln_relu_kernel(
    const u16* __restrict__ ctx, const float* __restrict__ gamma,
    const float* __restrict__ beta, float* __restrict__ out)
{
  const u16* x = ctx + (size_t)blockIdx.x * CD;
  const int t = threadIdx.x;
  const ushort4 uv = ((const ushort4*)x)[t];
  float v0 = bf2f(uv.x), v1 = bf2f(uv.y), v2 = bf2f(uv.z), v3 = bf2f(uv.w);
  float s = v0 + v1 + v2 + v3;
  float q = v0 * v0 + v1 * v1 + v2 * v2 + v3 * v3;
#pragma unroll
  for (int off = 1; off < 64; off <<= 1) {
    s += __shfl_xor(s, off);
    q += __shfl_xor(q, off);
  }
  __shared__ float ss[4], qq[4];
  const int w = t >> 6, lane = t & 63;
  if (lane == 0) { ss[w] = s; qq[w] = q; }
  __syncthreads();
  s = ss[0] + ss[1] + ss[2] + ss[3];
  q = qq[0] + qq[1] + qq[2] + qq[3];
  const float mean = s * (1.0f / CD);
  const float var  = q * (1.0f / CD) - mean * mean;
  const float rstd = rsqrtf(var + 1e-5f);
  const float4 g  = ((const float4*)gamma)[t];
  const float4 bb = ((const float4*)beta)[t];
  float4 o;
  o.x = fmaxf(0.f, (v0 - mean) * rstd * g.x + bb.x);
  o.y = fmaxf(0.f, (v1 - mean) * rstd * g.y + bb.y);
  o.z = fmaxf(0.f, (v2 - mean) * rstd * g.z + bb.z);
  o.w = fmaxf(0.f, (v3 - mean) * rstd * g.w + bb.w);
  ((float4*)(out + (size_t)blockIdx.x * CD))[t] = o;
}

// ---------------------------------------------------------------------------
extern "C" void kernel_launch(void* const* d_in, const int* in_sizes, int n_in,
                              void* d_out, int out_size, void* d_ws, size_t ws_size,
                              hipStream_t stream)
{
  (void)in_sizes; (void)n_in; (void)out_size; (void)ws_size;
  const float* x1    = (const float*)d_in[0];
  const float* x2    = (const float*)d_in[1];
  const float* Wq    = (const float*)d_in[2];
  const float* bq    = (const float*)d_in[3];
  const float* Wk    = (const float*)d_in[4];
  const float* bk    = (const float*)d_in[5];
  const float* Wv    = (const float*)d_in[6];
  const float* bv    = (const float*)d_in[7];
  const float* gamma = (const float*)d_in[8];
  const float* beta  = (const float*)d_in[9];
  float* out = (float*)d_out;

  const int LDS_BIG = 131072, LDS_MID = 98304;
  hipFuncSetAttribute((const void*)qk_kernel,
                      hipFuncAttributeMaxDynamicSharedMemorySize, LDS_BIG);
  hipFuncSetAttribute((const void*)scores_kernel,
                      hipFuncAttributeMaxDynamicSharedMemorySize, LDS_BIG);
  hipFuncSetAttribute((const void*)v_kernel,
                      hipFuncAttributeMaxDynamicSharedMemorySize, LDS_MID);
  hipFuncSetAttribute((const void*)pv_kernel,
                      hipFuncAttributeMaxDynamicSharedMemorySize, LDS_MID);

  char* p = (char*)d_ws;
  auto alloc = [&](size_t bytes) -> char* {
    char* r = p;
    p += (bytes + 255) & ~(size_t)255;
    return r;
  };
  u8*  x1f8  = (u8*)alloc((size_t)CM * CD);
  u8*  x2f8  = (u8*)alloc((size_t)CM * CD);
  u8*  WqT8  = (u8*)alloc((size_t)CD * CD);
  u8*  WkT8  = (u8*)alloc((size_t)CD * CD);
  u8*  WvT8  = (u8*)alloc((size_t)CD * CD);
  u8*  Qf8   = (u8*)alloc((size_t)CM * CD);
  u8*  Kf8   = (u8*)alloc((size_t)CM * CD);
  u8*  Vt8   = (u8*)alloc((size_t)CM * CD);
  u8*  Pf8   = (u8*)alloc((size_t)CB * CN * CN);
  u16* ctxb  = (u16*)alloc((size_t)CM * CD * 2);
  float* ls  = (float*)alloc((size_t)CB * CN * 4);
  float* vs  = (float*)alloc((size_t)CB * CD * 4);
  float* cs  = (float*)alloc((size_t)CB * CD * 4);

  // W transposes -> fp8 + zero csum (must precede cvt)
  {
    dim3 g(32, 32, 3), blk(32, 8);
    transpose_w_kernel<<<g, blk, 0, stream>>>(Wq, Wk, Wv, WqT8, WkT8, WvT8, cs);
  }

  // f32 -> fp8 inputs + exact colsum(x2) partials + zero lsum
  {
    dim3 g(256, 2);
    cvt_kernel<<<g, 256, 0, stream>>>(x1, x1f8, x2, x2f8, cs, ls);
  }

  // exact vsum = colsum(x2).Wv + 2048*bv  (f32)
  {
    dim3 g(8, CB);
    vsum_mv_kernel<<<g, 256, 0, stream>>>(cs, Wv, bv, vs);
  }

  // fused Q|K projections (fp8, 256 blocks)
  {
    dim3 g(32, 8);
    qk_kernel<<<g, 512, LDS_BIG, stream>>>(x1f8, x2f8, WqT8, WkT8, bq, bk,
                                           Qf8, Kf8);
  }

  // V projection -> Vt8 (fp8, 256 blocks)
  {
    dim3 g(32, 8);
    v_kernel<<<g, 512, LDS_MID, stream>>>(x2f8, WvT8, bv, Vt8);
  }

  // P/4 = exp(QK^T/32)/4 (fp8), l = rowsum
  {
    dim3 g(8, 8, CB);
    scores_kernel<<<g, 512, LDS_BIG, stream>>>(Qf8, Kf8, Pf8, ls);
  }

  // ctx = (vsum - 4*P@V/l)/(N-1) -> bf16
  {
    dim3 g(8, 8, CB);
    pv_kernel<<<g, 512, LDS_MID, stream>>>(Pf8, Vt8, ls, vs, ctxb);
  }

  // LayerNorm + ReLU (bf16 in, f32 out)
  ln_relu_kernel<<<CM, 256, 0, stream>>>(ctxb, gamma, beta, out);
}